// Round 5
// baseline (751.827 us; speedup 1.0000x reference)
//
#include <hip/hip_runtime.h>

#define N_TOK 16384
#define HIDN  768
#define MIDN  5376
#define COMBN 3840
#define NH    12
#define DHD   64
#define CHUNK 256
#define WIN   256

typedef short s16x8 __attribute__((ext_vector_type(8)));
typedef short s16x4 __attribute__((ext_vector_type(4)));
typedef float f32x4 __attribute__((ext_vector_type(4)));

__device__ __forceinline__ float bf2f(unsigned short u){
  union { unsigned u; float f; } x; x.u = ((unsigned)u) << 16; return x.f;
}
__device__ __forceinline__ unsigned short f2bf(float f){
  union { float f; unsigned u; } x; x.f = f;
  unsigned r = x.u + 0x7fffu + ((x.u >> 16) & 1u);
  return (unsigned short)(r >> 16);
}
__device__ __forceinline__ float gelu_fast(float x){
  float u = -1.5957691216057308f * (x + 0.044715f * x * x * x);
  return x / (1.f + __expf(u));
}
__device__ __forceinline__ void glds16(const void* g, void* l){
  __builtin_amdgcn_global_load_lds(
      (const __attribute__((address_space(1))) unsigned*)g,
      (__attribute__((address_space(3))) unsigned*)l, 16, 0, 0);
}

// ------- transpose + downcast: in fp32 [R][Cc] -> out bf16 [Cc][R] -------
__global__ __launch_bounds__(256) void transpose_f2b(
    const float* __restrict__ in, unsigned short* __restrict__ out,
    int R, int Cc)
{
  __shared__ short t[64 * 72];
  const int tid = threadIdx.x;
  const int r0 = blockIdx.y * 64, c0 = blockIdx.x * 64;
  #pragma unroll
  for (int rep = 0; rep < 4; rep++){
    int v = tid + 256 * rep;
    int r = v >> 4, s = v & 15;
    float4 d = *(const float4*)(in + (size_t)(r0 + r) * Cc + c0 + s * 4);
    s16x4 o = { (short)f2bf(d.x), (short)f2bf(d.y), (short)f2bf(d.z), (short)f2bf(d.w) };
    *(s16x4*)(t + r * 72 + s * 4) = o;
  }
  __syncthreads();
  #pragma unroll
  for (int rep = 0; rep < 2; rep++){
    int v = tid + 256 * rep;
    int c = v & 63, s2 = v >> 6;
    s16x8 d;
    #pragma unroll
    for (int j = 0; j < 8; j++) d[j] = t[(s2 * 8 + j) * 72 + c];
    *(s16x8*)(out + (size_t)(c0 + c) * R + r0 + s2 * 8) = d;
  }
}

// ------- layernorm: fp32 in -> bf16 out, one wave per row -------
__global__ __launch_bounds__(256) void ln_kernel(
    const float* __restrict__ x, const float* __restrict__ sc,
    const float* __restrict__ ofs, unsigned short* __restrict__ xn)
{
  const int lane = threadIdx.x & 63, wv = threadIdx.x >> 6;
  const int row = blockIdx.x * 4 + wv;
  const float4* xr = (const float4*)(x + (size_t)row * HIDN);
  float4 vals[3];
  float sum = 0.f, sq = 0.f;
  #pragma unroll
  for (int j = 0; j < 3; j++){
    vals[j] = xr[lane + 64 * j];
    sum += vals[j].x + vals[j].y + vals[j].z + vals[j].w;
    sq  += vals[j].x * vals[j].x + vals[j].y * vals[j].y
         + vals[j].z * vals[j].z + vals[j].w * vals[j].w;
  }
  #pragma unroll
  for (int o = 1; o < 64; o <<= 1){ sum += __shfl_xor(sum, o); sq += __shfl_xor(sq, o); }
  const float mu = sum * (1.f / HIDN);
  const float rs = rsqrtf(fmaxf(sq * (1.f / HIDN) - mu * mu, 0.f) + 1e-5f);
  s16x4* xo = (s16x4*)(xn + (size_t)row * HIDN);
  const float4* scp = (const float4*)sc;
  const float4* ofp = (const float4*)ofs;
  #pragma unroll
  for (int j = 0; j < 3; j++){
    int p = lane + 64 * j;
    float4 s = scp[p], o = ofp[p];
    s16x4 w;
    w[0] = (short)f2bf((vals[j].x - mu) * rs * s.x + o.x);
    w[1] = (short)f2bf((vals[j].y - mu) * rs * s.y + o.y);
    w[2] = (short)f2bf((vals[j].z - mu) * rs * s.z + o.z);
    w[3] = (short)f2bf((vals[j].w - mu) * rs * s.w + o.w);
    xo[p] = w;
  }
}

// ============================================================================
// 256x256 tile, BK=32, 4 LDS buffers, 3-tiles-ahead prefetch, 1 barrier/tile.
// 512 threads = 8 waves as 2(M)x4(N); per-wave 128x64 output = acc[8][4].
// LDS: single 128 KiB region; A = first 64 KiB (4 buf x 256x32 bf16),
// B = second 64 KiB. Swizzle as in R4 (verified): phys seg = seg^((row>>1)&3),
// inverse applied on global source col. Depth-3 is race-safe: stage(t+3)
// writes buf[(t-1)&3], whose last readers (a2 of tile t-1) completed before
// the iter-(t-1) barrier that precedes this iteration.
// Epilogue (gemm1): C-tile staged through the (now dead) 128 KiB LDS with an
// 8-col-granule XOR (bank-uniform readback), then stored as 16B/lane with
// each lane covering a contiguous 128B row-run -> full-line HBM writes.
// ============================================================================
template<int K>
__device__ __forceinline__ void gemm_pipe(
    const unsigned short* __restrict__ A, const unsigned short* __restrict__ BT,
    short* AsBuf, short* BsBuf,
    int tid, int quad, int l15, int wr, int wc, int m0, int n0,
    f32x4 acc[8][4])
{
  constexpr int T = K / 32;
  constexpr int BUFSZ = 256 * 32;            // shorts per buffer

  const int srow = tid >> 2;
  const int ksw  = ((tid & 3) ^ ((tid >> 3) & 3)) * 8;
  const unsigned short* Ap = A  + (size_t)(m0 + srow) * K + ksw;
  const unsigned short* Bp = BT + (size_t)(n0 + srow) * K + ksw;
  const size_t halfstep = (size_t)128 * K;

  auto stage = [&](int tt){
    char* Ad = ((char*)(AsBuf + (size_t)(tt & 3) * BUFSZ)) + tid * 16;
    char* Bd = ((char*)(BsBuf + (size_t)(tt & 3) * BUFSZ)) + tid * 16;
    const unsigned short* Asrc = Ap + tt * 32;
    const unsigned short* Bsrc = Bp + tt * 32;
    glds16(Asrc,            Ad);
    glds16(Asrc + halfstep, Ad + 8192);
    glds16(Bsrc,            Bd);
    glds16(Bsrc + halfstep, Bd + 8192);
  };

  const int seg = ((quad ^ ((l15 >> 1) & 3)) << 4);
  int offA[8], offB[4];
  #pragma unroll
  for (int mf = 0; mf < 8; mf++) offA[mf] = (wr * 128 + mf * 16 + l15) * 64 + seg;
  #pragma unroll
  for (int nf = 0; nf < 4; nf++) offB[nf] = (wc * 64 + nf * 16 + l15) * 64 + seg;

  stage(0); stage(1); stage(2);
  asm volatile("s_waitcnt vmcnt(8)" ::: "memory");
  asm volatile("s_barrier" ::: "memory");

  s16x8 a[4], a2[4], b[4];
  {
    const char* A0 = (const char*)AsBuf;
    const char* B0 = (const char*)BsBuf;
    #pragma unroll
    for (int i = 0; i < 4; i++) a[i] = *(const s16x8*)(A0 + offA[i]);
    #pragma unroll
    for (int j = 0; j < 4; j++) b[j] = *(const s16x8*)(B0 + offB[j]);
  }

  #pragma unroll 4
  for (int t = 0; t < T; t++){
    if (t + 3 < T) stage(t + 3);
    const char* Ab = (const char*)(AsBuf + (size_t)(t & 3) * BUFSZ);
    #pragma unroll
    for (int i = 0; i < 4; i++) a2[i] = *(const s16x8*)(Ab + offA[4 + i]);
    __builtin_amdgcn_s_setprio(1);
    #pragma unroll
    for (int i = 0; i < 4; i++)
      #pragma unroll
      for (int j = 0; j < 4; j++)
        acc[i][j] = __builtin_amdgcn_mfma_f32_16x16x32_bf16(a[i], b[j], acc[i][j], 0, 0, 0);
    #pragma unroll
    for (int i = 0; i < 4; i++)
      #pragma unroll
      for (int j = 0; j < 4; j++)
        acc[4 + i][j] = __builtin_amdgcn_mfma_f32_16x16x32_bf16(a2[i], b[j], acc[4 + i][j], 0, 0, 0);
    __builtin_amdgcn_s_setprio(0);
    if (t + 1 < T){
      if (t + 3 < T)      { asm volatile("s_waitcnt vmcnt(8)" ::: "memory"); }
      else if (t + 2 < T) { asm volatile("s_waitcnt vmcnt(4)" ::: "memory"); }
      else                { asm volatile("s_waitcnt vmcnt(0)" ::: "memory"); }
      asm volatile("s_barrier" ::: "memory");
      const char* An = (const char*)(AsBuf + (size_t)((t + 1) & 3) * BUFSZ);
      const char* Bn = (const char*)(BsBuf + (size_t)((t + 1) & 3) * BUFSZ);
      #pragma unroll
      for (int i = 0; i < 4; i++) a[i] = *(const s16x8*)(An + offA[i]);
      #pragma unroll
      for (int j = 0; j < 4; j++) b[j] = *(const s16x8*)(Bn + offB[j]);
    }
  }
}

// ------- GEMM1: [16384x768] x [5376x768]^T -> q/k/v/comb(gelu) -------
__global__ __launch_bounds__(512, 2) void gemm1_k(
    const unsigned short* __restrict__ A, const unsigned short* __restrict__ BT,
    const float* __restrict__ bias,
    unsigned short* __restrict__ qb, unsigned short* __restrict__ kb,
    unsigned short* __restrict__ vb, unsigned short* __restrict__ comb)
{
  __shared__ short SM[65536];                 // 128 KiB: A bufs | B bufs
  const int tid = threadIdx.x, lane = tid & 63, wv = tid >> 6;
  const int quad = lane >> 4, l15 = lane & 15;
  const int wr = wv >> 2, wc = wv & 3;

  // XCD-chunked bijective swizzle (nwg = 21*64 = 1344, % 8 == 0)
  const int nbx = gridDim.x;
  const int nwg = nbx * gridDim.y;
  const int bid = blockIdx.x + blockIdx.y * nbx;
  const int swzb = (bid & 7) * (nwg >> 3) + (bid >> 3);
  const int n0 = (swzb % nbx) * 256, m0 = (swzb / nbx) * 256;

  f32x4 acc[8][4];
  #pragma unroll
  for (int i = 0; i < 8; i++)
    #pragma unroll
    for (int j = 0; j < 4; j++) acc[i][j] = (f32x4){0.f,0.f,0.f,0.f};

  gemm_pipe<HIDN>(A, BT, &SM[0], &SM[32768], tid, quad, l15, wr, wc, m0, n0, acc);

  unsigned short* dstb; int cb; bool isff = false;
  if (n0 < 768)       { dstb = qb;   cb = n0; }
  else if (n0 < 1536) { dstb = kb;   cb = n0 - 768; }
  else if (n0 < 2304) { dstb = vb;   cb = n0 - 1536; }
  else                { dstb = comb; cb = n0 - 1536; isff = true; }
  const int rowstride = isff ? COMBN : HIDN;

  // ---- coalesced epilogue: stage C through LDS, store full rows ----
  __syncthreads();                            // all K-loop LDS reads consumed
  short* Cs = &SM[0];                         // 256 rows x 256 cols bf16
  #pragma unroll
  for (int nf = 0; nf < 4; nf++){
    const int col = wc * 64 + nf * 16 + l15;
    const float bsv = bias[n0 + col];
    #pragma unroll
    for (int mf = 0; mf < 8; mf++){
      #pragma unroll
      for (int r = 0; r < 4; r++){
        const int row = wr * 128 + mf * 16 + quad * 4 + r;
        float val = acc[mf][nf][r] + bsv;
        if (isff) val = gelu_fast(val);
        const int c8 = (col >> 3) ^ (row & 7);      // 8-col-granule XOR
        Cs[row * 256 + c8 * 8 + (col & 7)] = f2bf(val);
      }
    }
  }
  __syncthreads();
  {
    const int row = tid >> 1, ch = (tid & 1) * 16; // half-row: 16 x 8 cols
    unsigned short* gout = dstb + (size_t)(m0 + row) * rowstride + cb;
    #pragma unroll
    for (int k = 0; k < 16; k++){
      const int c8 = ch + k;
      s16x8 v = *(const s16x8*)(Cs + row * 256 + ((c8 ^ (row & 7)) * 8));
      *(s16x8*)(gout + c8 * 8) = v;
    }
  }
}

// ------- GEMM2: [16384x3840] x [768x3840]^T + b + xn residual -> fp32 -------
__global__ __launch_bounds__(512, 2) void gemm2_k(
    const unsigned short* __restrict__ A, const unsigned short* __restrict__ BT,
    const float* __restrict__ bias, const unsigned short* __restrict__ xn,
    float* __restrict__ outp)
{
  __shared__ short SM[65536];
  const int tid = threadIdx.x, lane = tid & 63, wv = tid >> 6;
  const int quad = lane >> 4, l15 = lane & 15;
  const int wr = wv >> 2, wc = wv & 3;

  // XCD-chunked bijective swizzle (nwg = 3*64 = 192, % 8 == 0)
  const int nbx = gridDim.x;
  const int nwg = nbx * gridDim.y;
  const int bid = blockIdx.x + blockIdx.y * nbx;
  const int swzb = (bid & 7) * (nwg >> 3) + (bid >> 3);
  const int n0 = (swzb % nbx) * 256, m0 = (swzb / nbx) * 256;

  f32x4 acc[8][4];
  #pragma unroll
  for (int i = 0; i < 8; i++)
    #pragma unroll
    for (int j = 0; j < 4; j++) acc[i][j] = (f32x4){0.f,0.f,0.f,0.f};

  gemm_pipe<COMBN>(A, BT, &SM[0], &SM[32768], tid, quad, l15, wr, wc, m0, n0, acc);

  // fp32 stores: 16 lanes x 4B = 64B segments -> already line-coalesced
  #pragma unroll
  for (int nf = 0; nf < 4; nf++){
    const int col = n0 + wc * 64 + nf * 16 + l15;
    const float bsv = bias[col];
    #pragma unroll
    for (int mf = 0; mf < 8; mf++){
      #pragma unroll
      for (int r = 0; r < 4; r++){
        const int row = m0 + wr * 128 + mf * 16 + quad * 4 + r;
        const size_t o = (size_t)row * HIDN + col;
        outp[o] = bf2f(xn[o]) + acc[mf][nf][r] + bsv;
      }
    }
  }
}

// ------- pre-rotate Q (with 1/8 scale) and K in place; layout [tok][768] -------
__global__ __launch_bounds__(384) void rope_qk(
    unsigned short* __restrict__ qb, unsigned short* __restrict__ kb,
    const float* __restrict__ psin, const float* __restrict__ pcos)
{
  __shared__ float ss[2048], cs[2048];
  const int tid = threadIdx.x, g = blockIdx.x;
  #pragma unroll
  for (int rep = 0; rep < 6; rep++){
    int idx = rep * 384 + tid;
    if (idx < 2048){
      int tok = idx >> 5, p = idx & 31;
      size_t gt = ((size_t)(g * 64 + tok)) * DHD + 2 * p;
      ss[idx] = psin[gt];
      cs[idx] = pcos[gt];
    }
  }
  __syncthreads();
  const int p = tid & 31;
  unsigned* q32 = (unsigned*)qb;
  unsigned* k32 = (unsigned*)kb;
  for (int tok = 0; tok < 64; tok++){
    const size_t a = ((size_t)(g * 64 + tok)) * 384 + tid;
    const float s = ss[tok * 32 + p], c0 = cs[tok * 32 + p];
    unsigned u = q32[a];
    float e = bf2f((unsigned short)(u & 0xffff));
    float d = bf2f((unsigned short)(u >> 16));
    q32[a] = (unsigned)f2bf((e * c0 - d * s) * 0.125f)
           | (((unsigned)f2bf((d * c0 + e * s) * 0.125f)) << 16);
    u = k32[a];
    e = bf2f((unsigned short)(u & 0xffff));
    d = bf2f((unsigned short)(u >> 16));
    k32[a] = (unsigned)f2bf(e * c0 - d * s)
           | (((unsigned)f2bf(d * c0 + e * s)) << 16);
  }
}

// ------- chunked local attention: pre-roped Q/K [tok][768], 64-key tiles -------
__global__ __launch_bounds__(256) void attn_kernel(
    const unsigned short* __restrict__ qb, const unsigned short* __restrict__ kb,
    const unsigned short* __restrict__ vb, unsigned short* __restrict__ comb,
    const int* __restrict__ lenp)
{
  __shared__ short Ks[2][64 * 72];
  __shared__ short Vt[2][64 * 64];
  __shared__ short Ps[4][16 * 72];
  const int tid = threadIdx.x, lane = tid & 63, wv = tid >> 6;
  const int quad = lane >> 4, l15 = lane & 15;

  // XCD-chunked swizzle (nwg = 64*12 = 768, % 8 == 0): consecutive chunks of
  // the same head land on one XCD -> 50% K/V window overlap is L2-resident.
  const int nwg = gridDim.x * gridDim.y;
  const int bid = blockIdx.x + blockIdx.y * gridDim.x;
  const int swzb = (bid & 7) * (nwg >> 3) + (bid >> 3);
  const int c = swzb % gridDim.x, h = swzb / gridDim.x;

  const unsigned lm = ~((unsigned)lenp[0] - 1u);
  const int i0 = c * CHUNK + wv * 64;
  const unsigned short* qh = qb + h * DHD;
  const unsigned short* kh = kb + h * DHD;
  const unsigned short* vh = vb + h * DHD;

  s16x8 qf[4][2];
  #pragma unroll
  for (int rt = 0; rt < 4; rt++){
    const unsigned short* qr = qh + (size_t)(i0 + rt * 16 + l15) * HIDN;
    qf[rt][0] = *(const s16x8*)(qr + quad * 8);
    qf[rt][1] = *(const s16x8*)(qr + 32 + quad * 8);
  }

  f32x4 O[4][4];
  float mm[4][4], ll[4][4];
  #pragma unroll
  for (int rt = 0; rt < 4; rt++)
    #pragma unroll
    for (int j = 0; j < 4; j++){ O[rt][j] = (f32x4){0,0,0,0}; mm[rt][j] = -1e30f; ll[rt][j] = 0.f; }
  short* myP = &Ps[wv][0];

  const int skey = tid & 63, sseg = tid >> 6;
  const int jb0 = c * CHUNK - 256;
  s16x8 kr[2], vr[2];

  auto issue = [&](int jb){
    if (jb >= 0){
      const unsigned short* kp = kh + (size_t)(jb + skey) * HIDN + sseg * 16;
      const unsigned short* vp = vh + (size_t)(jb + skey) * HIDN + sseg * 16;
      kr[0] = *(const s16x8*)(kp);     kr[1] = *(const s16x8*)(kp + 8);
      vr[0] = *(const s16x8*)(vp);     vr[1] = *(const s16x8*)(vp + 8);
    } else {
      kr[0] = kr[1] = vr[0] = vr[1] = (s16x8){0,0,0,0,0,0,0,0};
    }
  };

  issue(jb0);
  for (int tb = 0; tb < 8; tb++){
    const int jb = jb0 + tb * 64;
    const int buf = tb & 1;
    short* Kb = &Ks[buf][0];
    short* Vb = &Vt[buf][0];
    *(s16x8*)(Kb + skey * 72 + sseg * 16)     = kr[0];
    *(s16x8*)(Kb + skey * 72 + sseg * 16 + 8) = kr[1];
    #pragma unroll
    for (int half = 0; half < 2; half++)
      #pragma unroll
      for (int j = 0; j < 8; j++){
        const int d = sseg * 16 + half * 8 + j;
        Vb[d * 64 + (((skey & 56) ^ ((d & 7) << 3)) | (skey & 7))] = vr[half][j];
      }
    if (tb < 7) issue(jb + 64);
    __syncthreads();

    const bool act = (jb >= 0) && (jb <= i0 + 63) && (jb + 63 >= i0 - 255) &&
                     (((unsigned)i0 & lm) == ((unsigned)jb & lm));
    if (!act) continue;

    #pragma unroll
    for (int rt = 0; rt < 4; rt++){
      const int ilo = i0 + rt * 16;
      if (ilo + 15 < jb || ilo - (jb + 63) >= WIN) continue;
      f32x4 sc[4];
      #pragma unroll
      for (int ct = 0; ct < 4; ct++){
        const short* kbase = Kb + (ct * 16 + l15) * 72 + quad * 8;
        const s16x8 b0 = *(const s16x8*)(kbase);
        const s16x8 b1 = *(const s16x8*)(kbase + 32);
        f32x4 aa = (f32x4){0,0,0,0};
        aa = __builtin_amdgcn_mfma_f32_16x16x32_bf16(qf[rt][0], b0, aa, 0, 0, 0);
        aa = __builtin_amdgcn_mfma_f32_16x16x32_bf16(qf[rt][1], b1, aa, 0, 0, 0);
        sc[ct] = aa;
      }
      float alph[4];
      #pragma unroll
      for (int r = 0; r < 4; r++){
        const int i = ilo + quad * 4 + r;
        #pragma unroll
        for (int ct = 0; ct < 4; ct++){
          const unsigned dd = (unsigned)(i - (jb + ct * 16 + l15));
          if (dd >= 256u) sc[ct][r] = -1e30f;
        }
        float mx = fmaxf(fmaxf(sc[0][r], sc[1][r]), fmaxf(sc[2][r], sc[3][r]));
        mx = fmaxf(mx, __shfl_xor(mx, 1));
        mx = fmaxf(mx, __shfl_xor(mx, 2));
        mx = fmaxf(mx, __shfl_xor(mx, 4));
        mx = fmaxf(mx, __shfl_xor(mx, 8));
        const float mnew = fmaxf(mm[rt][r], mx);
        alph[r] = __expf(mm[rt][r] - mnew);
        mm[rt][r] = mnew;
        float p0 = __expf(sc[0][r] - mnew);
        float p1 = __expf(sc[1][r] - mnew);
        float p2 = __expf(sc[2][r] - mnew);
        float p3 = __expf(sc[3][r] - mnew);
        sc[0][r] = p0; sc[1][r] = p1; sc[2][r] = p2; sc[3][r] = p3;
        float rsum = (p0 + p1) + (p2 + p3);
        rsum += __shfl_xor(rsum, 1);
        rsum += __shfl_xor(rsum, 2);
        rsum += __shfl_xor(rsum, 4);
        rsum += __shfl_xor(rsum, 8);
        ll[rt][r] = ll[rt][r] * alph[r] + rsum;
      }
      #pragma unroll
      for (int co = 0; co < 4; co++)
        #pragma unroll
        for (int r = 0; r < 4; r++) O[rt][co][r] *= alph[r];
      #pragma unroll
      for (int r = 0; r < 4; r++){
        const int prow = quad * 4 + r;
        #pragma unroll
        for (int ct = 0; ct < 4; ct++)
          myP[prow * 72 + ct * 16 + l15] = (short)f2bf(sc[ct][r]);
      }
      #pragma unroll
      for (int ks2 = 0; ks2 < 2; ks2++){
        const s16x8 pf = *(const s16x8*)(myP + l15 * 72 + ks2 * 32 + quad * 8);
        #pragma unroll
        for (int co = 0; co < 4; co++){
          const int d = co * 16 + l15;
          const s16x8 vf = *(const s16x8*)(Vb + d * 64 +
                              ((ks2 * 32 + quad * 8) ^ ((d & 7) << 3)));
          O[rt][co] = __builtin_amdgcn_mfma_f32_16x16x32_bf16(pf, vf, O[rt][co], 0, 0, 0);
        }
      }
    }
  }

  #pragma unroll
  for (int rt = 0; rt < 4; rt++)
    #pragma unroll
    for (int co = 0; co < 4; co++)
      #pragma unroll
      for (int r = 0; r < 4; r++){
        const int tok = i0 + rt * 16 + quad * 4 + r;
        comb[(size_t)tok * COMBN + h * DHD + co * 16 + l15] = f2bf(O[rt][co][r] / ll[rt][r]);
      }
}

extern "C" void kernel_launch(void* const* d_in, const int* in_sizes, int n_in,
                              void* d_out, int out_size, void* d_ws, size_t ws_size,
                              hipStream_t stream)
{
  const float* x     = (const float*)d_in[0];
  const float* psin  = (const float*)d_in[2];
  const float* pcos  = (const float*)d_in[3];
  const float* lns   = (const float*)d_in[4];
  const float* lno   = (const float*)d_in[5];
  const float* w_in  = (const float*)d_in[6];
  const float* b_in  = (const float*)d_in[7];
  const float* w_out = (const float*)d_in[8];
  const float* b_out = (const float*)d_in[9];
  const int*   lenp  = (const int*)d_in[10];
  float* out = (float*)d_out;

  char* ws = (char*)d_ws;
  size_t off = 0;
  unsigned short* xn    = (unsigned short*)(ws + off); off += (size_t)N_TOK * HIDN * 2;
  unsigned short* wInT  = (unsigned short*)(ws + off); off += (size_t)MIDN * HIDN * 2;
  unsigned short* wOutT = (unsigned short*)(ws + off); off += (size_t)HIDN * COMBN * 2;
  unsigned short* qbuf  = (unsigned short*)(ws + off); off += (size_t)N_TOK * HIDN * 2;
  unsigned short* kbuf  = (unsigned short*)(ws + off); off += (size_t)N_TOK * HIDN * 2;
  unsigned short* vbuf  = (unsigned short*)(ws + off); off += (size_t)N_TOK * HIDN * 2;
  unsigned short* comb  = (unsigned short*)(ws + off); off += (size_t)N_TOK * COMBN * 2;

  transpose_f2b<<<dim3(MIDN/64, HIDN/64), 256, 0, stream>>>(w_in, wInT, HIDN, MIDN);
  transpose_f2b<<<dim3(HIDN/64, COMBN/64), 256, 0, stream>>>(w_out, wOutT, COMBN, HIDN);
  ln_kernel<<<dim3(N_TOK/4), 256, 0, stream>>>(x, lns, lno, xn);
  gemm1_k<<<dim3(MIDN/256, N_TOK/256), 512, 0, stream>>>(
      xn, wInT, b_in, qbuf, kbuf, vbuf, comb);
  rope_qk<<<dim3(N_TOK/64), 384, 0, stream>>>(qbuf, kbuf, psin, pcos);
  attn_kernel<<<dim3(N_TOK/CHUNK, NH), 256, 0, stream>>>(
      qbuf, kbuf, vbuf, comb, lenp);
  gemm2_k<<<dim3(HIDN/256, N_TOK/256), 512, 0, stream>>>(
      comb, wOutT, b_out, xn, out);
}

// Round 6
// 684.522 us; speedup vs baseline: 1.0983x; 1.0983x over previous
//
#include <hip/hip_runtime.h>

#define N_TOK 16384
#define HIDN  768
#define MIDN  5376
#define COMBN 3840
#define NH    12
#define DHD   64
#define CHUNK 256
#define WIN   256

typedef short s16x8 __attribute__((ext_vector_type(8)));
typedef short s16x4 __attribute__((ext_vector_type(4)));
typedef float f32x4 __attribute__((ext_vector_type(4)));

__device__ __forceinline__ float bf2f(unsigned short u){
  union { unsigned u; float f; } x; x.u = ((unsigned)u) << 16; return x.f;
}
__device__ __forceinline__ unsigned short f2bf(float f){
  union { float f; unsigned u; } x; x.f = f;
  unsigned r = x.u + 0x7fffu + ((x.u >> 16) & 1u);
  return (unsigned short)(r >> 16);
}
__device__ __forceinline__ float gelu_fast(float x){
  float u = -1.5957691216057308f * (x + 0.044715f * x * x * x);
  return x / (1.f + __expf(u));
}
__device__ __forceinline__ void glds16(const void* g, void* l){
  __builtin_amdgcn_global_load_lds(
      (const __attribute__((address_space(1))) unsigned*)g,
      (__attribute__((address_space(3))) unsigned*)l, 16, 0, 0);
}

// ------- transpose + downcast: in fp32 [R][Cc] -> out bf16 [Cc][R] -------
__global__ __launch_bounds__(256) void transpose_f2b(
    const float* __restrict__ in, unsigned short* __restrict__ out,
    int R, int Cc)
{
  __shared__ short t[64 * 72];
  const int tid = threadIdx.x;
  const int r0 = blockIdx.y * 64, c0 = blockIdx.x * 64;
  #pragma unroll
  for (int rep = 0; rep < 4; rep++){
    int v = tid + 256 * rep;
    int r = v >> 4, s = v & 15;
    float4 d = *(const float4*)(in + (size_t)(r0 + r) * Cc + c0 + s * 4);
    s16x4 o = { (short)f2bf(d.x), (short)f2bf(d.y), (short)f2bf(d.z), (short)f2bf(d.w) };
    *(s16x4*)(t + r * 72 + s * 4) = o;
  }
  __syncthreads();
  #pragma unroll
  for (int rep = 0; rep < 2; rep++){
    int v = tid + 256 * rep;
    int c = v & 63, s2 = v >> 6;
    s16x8 d;
    #pragma unroll
    for (int j = 0; j < 8; j++) d[j] = t[(s2 * 8 + j) * 72 + c];
    *(s16x8*)(out + (size_t)(c0 + c) * R + r0 + s2 * 8) = d;
  }
}

// ------- layernorm: fp32 in -> bf16 out, one wave per row -------
__global__ __launch_bounds__(256) void ln_kernel(
    const float* __restrict__ x, const float* __restrict__ sc,
    const float* __restrict__ ofs, unsigned short* __restrict__ xn)
{
  const int lane = threadIdx.x & 63, wv = threadIdx.x >> 6;
  const int row = blockIdx.x * 4 + wv;
  const float4* xr = (const float4*)(x + (size_t)row * HIDN);
  float4 vals[3];
  float sum = 0.f, sq = 0.f;
  #pragma unroll
  for (int j = 0; j < 3; j++){
    vals[j] = xr[lane + 64 * j];
    sum += vals[j].x + vals[j].y + vals[j].z + vals[j].w;
    sq  += vals[j].x * vals[j].x + vals[j].y * vals[j].y
         + vals[j].z * vals[j].z + vals[j].w * vals[j].w;
  }
  #pragma unroll
  for (int o = 1; o < 64; o <<= 1){ sum += __shfl_xor(sum, o); sq += __shfl_xor(sq, o); }
  const float mu = sum * (1.f / HIDN);
  const float rs = rsqrtf(fmaxf(sq * (1.f / HIDN) - mu * mu, 0.f) + 1e-5f);
  s16x4* xo = (s16x4*)(xn + (size_t)row * HIDN);
  const float4* scp = (const float4*)sc;
  const float4* ofp = (const float4*)ofs;
  #pragma unroll
  for (int j = 0; j < 3; j++){
    int p = lane + 64 * j;
    float4 s = scp[p], o = ofp[p];
    s16x4 w;
    w[0] = (short)f2bf((vals[j].x - mu) * rs * s.x + o.x);
    w[1] = (short)f2bf((vals[j].y - mu) * rs * s.y + o.y);
    w[2] = (short)f2bf((vals[j].z - mu) * rs * s.z + o.z);
    w[3] = (short)f2bf((vals[j].w - mu) * rs * s.w + o.w);
    xo[p] = w;
  }
}

// ============================================================================
// m97-shape GEMM: 128x128 tile, 256 threads = 4 waves (2Mx2N), acc[4][4]
// (64x64 per wave). LDS: single-buffered As[128x32]+Bs[128x32] = 16 KiB.
// ~150 regs incl acc + 16 KiB -> ~3 blocks/CU co-resident; the per-tile
// barrier drain is hidden by OTHER blocks' MFMA waves (m114 mechanism),
// not by in-block pipelining (which R1-R5 showed cannot exceed ~25% util
// at 1 block/CU).
// Swizzle (verified R1/R4, conflicts=0): 64B row = 4 segs of 16B;
// phys seg = seg ^ ((row>>1)&3); glds16 dest linear (tid*16), inverse
// swizzle on the GLOBAL source col: ksw = ((tid&3)^((tid>>3)&3))*8 elems.
// ============================================================================
template<int K>
__device__ __forceinline__ void gemm_tile128(
    const unsigned short* __restrict__ A, const unsigned short* __restrict__ BT,
    short* As, short* Bs,
    int tid, int quad, int l15, int wr, int wc, int m0, int n0,
    f32x4 acc[4][4])
{
  constexpr int T = K / 32;
  const int srow = tid >> 2;
  const int ksw  = ((tid & 3) ^ ((tid >> 3) & 3)) * 8;
  const unsigned short* Ap = A  + (size_t)(m0 + srow) * K + ksw;
  const unsigned short* Bp = BT + (size_t)(n0 + srow) * K + ksw;
  const size_t hstep = (size_t)64 * K;
  char* Ad = ((char*)As) + tid * 16;
  char* Bd = ((char*)Bs) + tid * 16;

  const int seg = ((quad ^ ((l15 >> 1) & 3)) << 4);
  int offA[4], offB[4];
  #pragma unroll
  for (int mf = 0; mf < 4; mf++) offA[mf] = (wr * 64 + mf * 16 + l15) * 64 + seg;
  #pragma unroll
  for (int nf = 0; nf < 4; nf++) offB[nf] = (wc * 64 + nf * 16 + l15) * 64 + seg;

  for (int t = 0; t < T; t++){
    __syncthreads();                       // prev tile's ds_reads complete
    glds16(Ap + t * 32,         Ad);
    glds16(Ap + t * 32 + hstep, Ad + 4096);
    glds16(Bp + t * 32,         Bd);
    glds16(Bp + t * 32 + hstep, Bd + 4096);
    __syncthreads();                       // staging landed (vmcnt drain --
                                           // hidden by co-resident blocks)
    s16x8 a[4], b[4];
    #pragma unroll
    for (int i = 0; i < 4; i++) a[i] = *(const s16x8*)(((const char*)As) + offA[i]);
    #pragma unroll
    for (int j = 0; j < 4; j++) b[j] = *(const s16x8*)(((const char*)Bs) + offB[j]);
    #pragma unroll
    for (int i = 0; i < 4; i++)
      #pragma unroll
      for (int j = 0; j < 4; j++)
        acc[i][j] = __builtin_amdgcn_mfma_f32_16x16x32_bf16(a[i], b[j], acc[i][j], 0, 0, 0);
  }
}

// ------- GEMM1: [16384x768] x [5376x768]^T -> q/k/v/comb(gelu) -------
__global__ __launch_bounds__(256, 3) void gemm1_k(
    const unsigned short* __restrict__ A, const unsigned short* __restrict__ BT,
    const float* __restrict__ bias,
    unsigned short* __restrict__ qb, unsigned short* __restrict__ kb,
    unsigned short* __restrict__ vb, unsigned short* __restrict__ comb)
{
  __shared__ short As[128 * 32];
  __shared__ short Bs[128 * 32];
  const int tid = threadIdx.x, lane = tid & 63, wv = tid >> 6;
  const int quad = lane >> 4, l15 = lane & 15;
  const int wr = wv >> 1, wc = wv & 1;
  const int n0 = blockIdx.x * 128, m0 = blockIdx.y * 128;

  f32x4 acc[4][4];
  #pragma unroll
  for (int i = 0; i < 4; i++)
    #pragma unroll
    for (int j = 0; j < 4; j++) acc[i][j] = (f32x4){0.f,0.f,0.f,0.f};

  gemm_tile128<HIDN>(A, BT, As, Bs, tid, quad, l15, wr, wc, m0, n0, acc);

  // block-uniform output class (boundaries 768/1536/2304 are multiples of 128)
  unsigned short* dstb; int cb; bool isff = false;
  if (n0 < 768)       { dstb = qb;   cb = n0; }
  else if (n0 < 1536) { dstb = kb;   cb = n0 - 768; }
  else if (n0 < 2304) { dstb = vb;   cb = n0 - 1536; }
  else                { dstb = comb; cb = n0 - 1536; isff = true; }
  const int rowstride = isff ? COMBN : HIDN;

  #pragma unroll
  for (int nf = 0; nf < 4; nf++){
    const int colg = n0 + wc * 64 + nf * 16 + l15;
    const float bsv = bias[colg];
    const int col = cb + wc * 64 + nf * 16 + l15;
    #pragma unroll
    for (int mf = 0; mf < 4; mf++){
      #pragma unroll
      for (int r = 0; r < 4; r++){
        const int row = m0 + wr * 64 + mf * 16 + quad * 4 + r;
        float val = acc[mf][nf][r] + bsv;
        if (isff) val = gelu_fast(val);
        dstb[(size_t)row * rowstride + col] = f2bf(val);
      }
    }
  }
}

// ------- GEMM2: [16384x3840] x [768x3840]^T + b + xn residual -> fp32 -------
__global__ __launch_bounds__(256, 3) void gemm2_k(
    const unsigned short* __restrict__ A, const unsigned short* __restrict__ BT,
    const float* __restrict__ bias, const unsigned short* __restrict__ xn,
    float* __restrict__ outp)
{
  __shared__ short As[128 * 32];
  __shared__ short Bs[128 * 32];
  const int tid = threadIdx.x, lane = tid & 63, wv = tid >> 6;
  const int quad = lane >> 4, l15 = lane & 15;
  const int wr = wv >> 1, wc = wv & 1;
  const int n0 = blockIdx.x * 128, m0 = blockIdx.y * 128;

  f32x4 acc[4][4];
  #pragma unroll
  for (int i = 0; i < 4; i++)
    #pragma unroll
    for (int j = 0; j < 4; j++) acc[i][j] = (f32x4){0.f,0.f,0.f,0.f};

  gemm_tile128<COMBN>(A, BT, As, Bs, tid, quad, l15, wr, wc, m0, n0, acc);

  #pragma unroll
  for (int nf = 0; nf < 4; nf++){
    const int col = n0 + wc * 64 + nf * 16 + l15;
    const float bsv = bias[col];
    #pragma unroll
    for (int mf = 0; mf < 4; mf++){
      #pragma unroll
      for (int r = 0; r < 4; r++){
        const int row = m0 + wr * 64 + mf * 16 + quad * 4 + r;
        const size_t o = (size_t)row * HIDN + col;
        outp[o] = bf2f(xn[o]) + acc[mf][nf][r] + bsv;
      }
    }
  }
}

// ------- pre-rotate Q (with 1/8 scale) and K in place; layout [tok][768] -------
__global__ __launch_bounds__(384) void rope_qk(
    unsigned short* __restrict__ qb, unsigned short* __restrict__ kb,
    const float* __restrict__ psin, const float* __restrict__ pcos)
{
  __shared__ float ss[2048], cs[2048];
  const int tid = threadIdx.x, g = blockIdx.x;
  #pragma unroll
  for (int rep = 0; rep < 6; rep++){
    int idx = rep * 384 + tid;
    if (idx < 2048){
      int tok = idx >> 5, p = idx & 31;
      size_t gt = ((size_t)(g * 64 + tok)) * DHD + 2 * p;
      ss[idx] = psin[gt];
      cs[idx] = pcos[gt];
    }
  }
  __syncthreads();
  const int p = tid & 31;
  unsigned* q32 = (unsigned*)qb;
  unsigned* k32 = (unsigned*)kb;
  for (int tok = 0; tok < 64; tok++){
    const size_t a = ((size_t)(g * 64 + tok)) * 384 + tid;
    const float s = ss[tok * 32 + p], c0 = cs[tok * 32 + p];
    unsigned u = q32[a];
    float e = bf2f((unsigned short)(u & 0xffff));
    float d = bf2f((unsigned short)(u >> 16));
    q32[a] = (unsigned)f2bf((e * c0 - d * s) * 0.125f)
           | (((unsigned)f2bf((d * c0 + e * s) * 0.125f)) << 16);
    u = k32[a];
    e = bf2f((unsigned short)(u & 0xffff));
    d = bf2f((unsigned short)(u >> 16));
    k32[a] = (unsigned)f2bf(e * c0 - d * s)
           | (((unsigned)f2bf(d * c0 + e * s)) << 16);
  }
}

// ------- chunked local attention: pre-roped Q/K [tok][768], 64-key tiles -------
__global__ __launch_bounds__(256) void attn_kernel(
    const unsigned short* __restrict__ qb, const unsigned short* __restrict__ kb,
    const unsigned short* __restrict__ vb, unsigned short* __restrict__ comb,
    const int* __restrict__ lenp)
{
  __shared__ short Ks[2][64 * 72];
  __shared__ short Vt[2][64 * 64];
  __shared__ short Ps[4][16 * 72];
  const int tid = threadIdx.x, lane = tid & 63, wv = tid >> 6;
  const int quad = lane >> 4, l15 = lane & 15;
  const int h = blockIdx.y, c = blockIdx.x;
  const unsigned lm = ~((unsigned)lenp[0] - 1u);
  const int i0 = c * CHUNK + wv * 64;
  const unsigned short* qh = qb + h * DHD;
  const unsigned short* kh = kb + h * DHD;
  const unsigned short* vh = vb + h * DHD;

  s16x8 qf[4][2];
  #pragma unroll
  for (int rt = 0; rt < 4; rt++){
    const unsigned short* qr = qh + (size_t)(i0 + rt * 16 + l15) * HIDN;
    qf[rt][0] = *(const s16x8*)(qr + quad * 8);
    qf[rt][1] = *(const s16x8*)(qr + 32 + quad * 8);
  }

  f32x4 O[4][4];
  float mm[4][4], ll[4][4];
  #pragma unroll
  for (int rt = 0; rt < 4; rt++)
    #pragma unroll
    for (int j = 0; j < 4; j++){ O[rt][j] = (f32x4){0,0,0,0}; mm[rt][j] = -1e30f; ll[rt][j] = 0.f; }
  short* myP = &Ps[wv][0];

  const int skey = tid & 63, sseg = tid >> 6;
  const int jb0 = c * CHUNK - 256;
  s16x8 kr[2], vr[2];

  auto issue = [&](int jb){
    if (jb >= 0){
      const unsigned short* kp = kh + (size_t)(jb + skey) * HIDN + sseg * 16;
      const unsigned short* vp = vh + (size_t)(jb + skey) * HIDN + sseg * 16;
      kr[0] = *(const s16x8*)(kp);     kr[1] = *(const s16x8*)(kp + 8);
      vr[0] = *(const s16x8*)(vp);     vr[1] = *(const s16x8*)(vp + 8);
    } else {
      kr[0] = kr[1] = vr[0] = vr[1] = (s16x8){0,0,0,0,0,0,0,0};
    }
  };

  issue(jb0);
  for (int tb = 0; tb < 8; tb++){
    const int jb = jb0 + tb * 64;
    const int buf = tb & 1;
    short* Kb = &Ks[buf][0];
    short* Vb = &Vt[buf][0];
    *(s16x8*)(Kb + skey * 72 + sseg * 16)     = kr[0];
    *(s16x8*)(Kb + skey * 72 + sseg * 16 + 8) = kr[1];
    #pragma unroll
    for (int half = 0; half < 2; half++)
      #pragma unroll
      for (int j = 0; j < 8; j++){
        const int d = sseg * 16 + half * 8 + j;
        Vb[d * 64 + (((skey & 56) ^ ((d & 7) << 3)) | (skey & 7))] = vr[half][j];
      }
    if (tb < 7) issue(jb + 64);
    __syncthreads();

    const bool act = (jb >= 0) && (jb <= i0 + 63) && (jb + 63 >= i0 - 255) &&
                     (((unsigned)i0 & lm) == ((unsigned)jb & lm));
    if (!act) continue;

    #pragma unroll
    for (int rt = 0; rt < 4; rt++){
      const int ilo = i0 + rt * 16;
      if (ilo + 15 < jb || ilo - (jb + 63) >= WIN) continue;
      f32x4 sc[4];
      #pragma unroll
      for (int ct = 0; ct < 4; ct++){
        const short* kbase = Kb + (ct * 16 + l15) * 72 + quad * 8;
        const s16x8 b0 = *(const s16x8*)(kbase);
        const s16x8 b1 = *(const s16x8*)(kbase + 32);
        f32x4 aa = (f32x4){0,0,0,0};
        aa = __builtin_amdgcn_mfma_f32_16x16x32_bf16(qf[rt][0], b0, aa, 0, 0, 0);
        aa = __builtin_amdgcn_mfma_f32_16x16x32_bf16(qf[rt][1], b1, aa, 0, 0, 0);
        sc[ct] = aa;
      }
      float alph[4];
      #pragma unroll
      for (int r = 0; r < 4; r++){
        const int i = ilo + quad * 4 + r;
        #pragma unroll
        for (int ct = 0; ct < 4; ct++){
          const unsigned dd = (unsigned)(i - (jb + ct * 16 + l15));
          if (dd >= 256u) sc[ct][r] = -1e30f;
        }
        float mx = fmaxf(fmaxf(sc[0][r], sc[1][r]), fmaxf(sc[2][r], sc[3][r]));
        mx = fmaxf(mx, __shfl_xor(mx, 1));
        mx = fmaxf(mx, __shfl_xor(mx, 2));
        mx = fmaxf(mx, __shfl_xor(mx, 4));
        mx = fmaxf(mx, __shfl_xor(mx, 8));
        const float mnew = fmaxf(mm[rt][r], mx);
        alph[r] = __expf(mm[rt][r] - mnew);
        mm[rt][r] = mnew;
        float p0 = __expf(sc[0][r] - mnew);
        float p1 = __expf(sc[1][r] - mnew);
        float p2 = __expf(sc[2][r] - mnew);
        float p3 = __expf(sc[3][r] - mnew);
        sc[0][r] = p0; sc[1][r] = p1; sc[2][r] = p2; sc[3][r] = p3;
        float rsum = (p0 + p1) + (p2 + p3);
        rsum += __shfl_xor(rsum, 1);
        rsum += __shfl_xor(rsum, 2);
        rsum += __shfl_xor(rsum, 4);
        rsum += __shfl_xor(rsum, 8);
        ll[rt][r] = ll[rt][r] * alph[r] + rsum;
      }
      #pragma unroll
      for (int co = 0; co < 4; co++)
        #pragma unroll
        for (int r = 0; r < 4; r++) O[rt][co][r] *= alph[r];
      #pragma unroll
      for (int r = 0; r < 4; r++){
        const int prow = quad * 4 + r;
        #pragma unroll
        for (int ct = 0; ct < 4; ct++)
          myP[prow * 72 + ct * 16 + l15] = (short)f2bf(sc[ct][r]);
      }
      #pragma unroll
      for (int ks2 = 0; ks2 < 2; ks2++){
        const s16x8 pf = *(const s16x8*)(myP + l15 * 72 + ks2 * 32 + quad * 8);
        #pragma unroll
        for (int co = 0; co < 4; co++){
          const int d = co * 16 + l15;
          const s16x8 vf = *(const s16x8*)(Vb + d * 64 +
                              ((ks2 * 32 + quad * 8) ^ ((d & 7) << 3)));
          O[rt][co] = __builtin_amdgcn_mfma_f32_16x16x32_bf16(pf, vf, O[rt][co], 0, 0, 0);
        }
      }
    }
  }

  #pragma unroll
  for (int rt = 0; rt < 4; rt++)
    #pragma unroll
    for (int co = 0; co < 4; co++)
      #pragma unroll
      for (int r = 0; r < 4; r++){
        const int tok = i0 + rt * 16 + quad * 4 + r;
        comb[(size_t)tok * COMBN + h * DHD + co * 16 + l15] = f2bf(O[rt][co][r] / ll[rt][r]);
      }
}

extern "C" void kernel_launch(void* const* d_in, const int* in_sizes, int n_in,
                              void* d_out, int out_size, void* d_ws, size_t ws_size,
                              hipStream_t stream)
{
  const float* x     = (const float*)d_in[0];
  const float* psin  = (const float*)d_in[2];
  const float* pcos  = (const float*)d_in[3];
  const float* lns   = (const float*)d_in[4];
  const float* lno   = (const float*)d_in[5];
  const float* w_in  = (const float*)d_in[6];
  const float* b_in  = (const float*)d_in[7];
  const float* w_out = (const float*)d_in[8];
  const float* b_out = (const float*)d_in[9];
  const int*   lenp  = (const int*)d_in[10];
  float* out = (float*)d_out;

  char* ws = (char*)d_ws;
  size_t off = 0;
  unsigned short* xn    = (unsigned short*)(ws + off); off += (size_t)N_TOK * HIDN * 2;
  unsigned short* wInT  = (unsigned short*)(ws + off); off += (size_t)MIDN * HIDN * 2;
  unsigned short* wOutT = (unsigned short*)(ws + off); off += (size_t)HIDN * COMBN * 2;
  unsigned short* qbuf  = (unsigned short*)(ws + off); off += (size_t)N_TOK * HIDN * 2;
  unsigned short* kbuf  = (unsigned short*)(ws + off); off += (size_t)N_TOK * HIDN * 2;
  unsigned short* vbuf  = (unsigned short*)(ws + off); off += (size_t)N_TOK * HIDN * 2;
  unsigned short* comb  = (unsigned short*)(ws + off); off += (size_t)N_TOK * COMBN * 2;

  transpose_f2b<<<dim3(MIDN/64, HIDN/64), 256, 0, stream>>>(w_in, wInT, HIDN, MIDN);
  transpose_f2b<<<dim3(HIDN/64, COMBN/64), 256, 0, stream>>>(w_out, wOutT, COMBN, HIDN);
  ln_kernel<<<dim3(N_TOK/4), 256, 0, stream>>>(x, lns, lno, xn);
  gemm1_k<<<dim3(MIDN/128, N_TOK/128), 256, 0, stream>>>(
      xn, wInT, b_in, qbuf, kbuf, vbuf, comb);
  rope_qk<<<dim3(N_TOK/64), 384, 0, stream>>>(qbuf, kbuf, psin, pcos);
  attn_kernel<<<dim3(N_TOK/CHUNK, NH), 256, 0, stream>>>(
      qbuf, kbuf, vbuf, comb, lenp);
  gemm2_k<<<dim3(HIDN/128, N_TOK/128), 256, 0, stream>>>(
      comb, wOutT, b_out, xn, out);
}

// Round 7
// 626.710 us; speedup vs baseline: 1.1996x; 1.0922x over previous
//
#include <hip/hip_runtime.h>

#define N_TOK 16384
#define HIDN  768
#define MIDN  5376
#define COMBN 3840
#define NH    12
#define DHD   64
#define CHUNK 256
#define WIN   256

typedef short s16x8 __attribute__((ext_vector_type(8)));
typedef short s16x4 __attribute__((ext_vector_type(4)));
typedef float f32x4 __attribute__((ext_vector_type(4)));

__device__ __forceinline__ float bf2f(unsigned short u){
  union { unsigned u; float f; } x; x.u = ((unsigned)u) << 16; return x.f;
}
__device__ __forceinline__ unsigned short f2bf(float f){
  union { float f; unsigned u; } x; x.f = f;
  unsigned r = x.u + 0x7fffu + ((x.u >> 16) & 1u);
  return (unsigned short)(r >> 16);
}
__device__ __forceinline__ float gelu_fast(float x){
  float u = -1.5957691216057308f * (x + 0.044715f * x * x * x);
  return x / (1.f + __expf(u));
}
__device__ __forceinline__ void glds16(const void* g, void* l){
  __builtin_amdgcn_global_load_lds(
      (const __attribute__((address_space(1))) unsigned*)g,
      (__attribute__((address_space(3))) unsigned*)l, 16, 0, 0);
}

// ------- transpose + downcast: in fp32 [R][Cc] -> out bf16 [Cc][R] -------
__global__ __launch_bounds__(256) void transpose_f2b(
    const float* __restrict__ in, unsigned short* __restrict__ out,
    int R, int Cc)
{
  __shared__ short t[64 * 72];
  const int tid = threadIdx.x;
  const int r0 = blockIdx.y * 64, c0 = blockIdx.x * 64;
  #pragma unroll
  for (int rep = 0; rep < 4; rep++){
    int v = tid + 256 * rep;
    int r = v >> 4, s = v & 15;
    float4 d = *(const float4*)(in + (size_t)(r0 + r) * Cc + c0 + s * 4);
    s16x4 o = { (short)f2bf(d.x), (short)f2bf(d.y), (short)f2bf(d.z), (short)f2bf(d.w) };
    *(s16x4*)(t + r * 72 + s * 4) = o;
  }
  __syncthreads();
  #pragma unroll
  for (int rep = 0; rep < 2; rep++){
    int v = tid + 256 * rep;
    int c = v & 63, s2 = v >> 6;
    s16x8 d;
    #pragma unroll
    for (int j = 0; j < 8; j++) d[j] = t[(s2 * 8 + j) * 72 + c];
    *(s16x8*)(out + (size_t)(c0 + c) * R + r0 + s2 * 8) = d;
  }
}

// ------- layernorm: fp32 in -> bf16 out, one wave per row -------
__global__ __launch_bounds__(256) void ln_kernel(
    const float* __restrict__ x, const float* __restrict__ sc,
    const float* __restrict__ ofs, unsigned short* __restrict__ xn)
{
  const int lane = threadIdx.x & 63, wv = threadIdx.x >> 6;
  const int row = blockIdx.x * 4 + wv;
  const float4* xr = (const float4*)(x + (size_t)row * HIDN);
  float4 vals[3];
  float sum = 0.f, sq = 0.f;
  #pragma unroll
  for (int j = 0; j < 3; j++){
    vals[j] = xr[lane + 64 * j];
    sum += vals[j].x + vals[j].y + vals[j].z + vals[j].w;
    sq  += vals[j].x * vals[j].x + vals[j].y * vals[j].y
         + vals[j].z * vals[j].z + vals[j].w * vals[j].w;
  }
  #pragma unroll
  for (int o = 1; o < 64; o <<= 1){ sum += __shfl_xor(sum, o); sq += __shfl_xor(sq, o); }
  const float mu = sum * (1.f / HIDN);
  const float rs = rsqrtf(fmaxf(sq * (1.f / HIDN) - mu * mu, 0.f) + 1e-5f);
  s16x4* xo = (s16x4*)(xn + (size_t)row * HIDN);
  const float4* scp = (const float4*)sc;
  const float4* ofp = (const float4*)ofs;
  #pragma unroll
  for (int j = 0; j < 3; j++){
    int p = lane + 64 * j;
    float4 s = scp[p], o = ofp[p];
    s16x4 w;
    w[0] = (short)f2bf((vals[j].x - mu) * rs * s.x + o.x);
    w[1] = (short)f2bf((vals[j].y - mu) * rs * s.y + o.y);
    w[2] = (short)f2bf((vals[j].z - mu) * rs * s.z + o.z);
    w[3] = (short)f2bf((vals[j].w - mu) * rs * s.w + o.w);
    xo[p] = w;
  }
}

// ============================================================================
// m97-shape GEMM (unchanged from R6, best measured): 128x128 tile, 256
// threads = 4 waves (2Mx2N), acc[4][4], single 16 KiB LDS, ~3 blocks/CU.
// R7 changes are TRAFFIC-ONLY:
//  * gemm1 grid supertiling GROUP_M=16: consecutive blocks cover a 16(m) x
//    42(n) super-row -> B (8 MB) fetched ~once per group (8 groups) instead
//    of once per 128 m-rows: FETCH ideal ~100 MB (was 425 measured).
//  * epilogue loop order nf-INNER: each (mf,r) issues 4 back-to-back 32B
//    stores covering a contiguous 128B row-run -> full-line HBM writes
//    (was 1.7x write amplification with nf-outer).
// ============================================================================
template<int K>
__device__ __forceinline__ void gemm_tile128(
    const unsigned short* __restrict__ A, const unsigned short* __restrict__ BT,
    short* As, short* Bs,
    int tid, int quad, int l15, int wr, int wc, int m0, int n0,
    f32x4 acc[4][4])
{
  constexpr int T = K / 32;
  const int srow = tid >> 2;
  const int ksw  = ((tid & 3) ^ ((tid >> 3) & 3)) * 8;
  const unsigned short* Ap = A  + (size_t)(m0 + srow) * K + ksw;
  const unsigned short* Bp = BT + (size_t)(n0 + srow) * K + ksw;
  const size_t hstep = (size_t)64 * K;
  char* Ad = ((char*)As) + tid * 16;
  char* Bd = ((char*)Bs) + tid * 16;

  const int seg = ((quad ^ ((l15 >> 1) & 3)) << 4);
  int offA[4], offB[4];
  #pragma unroll
  for (int mf = 0; mf < 4; mf++) offA[mf] = (wr * 64 + mf * 16 + l15) * 64 + seg;
  #pragma unroll
  for (int nf = 0; nf < 4; nf++) offB[nf] = (wc * 64 + nf * 16 + l15) * 64 + seg;

  for (int t = 0; t < T; t++){
    __syncthreads();                       // prev tile's ds_reads complete
    glds16(Ap + t * 32,         Ad);
    glds16(Ap + t * 32 + hstep, Ad + 4096);
    glds16(Bp + t * 32,         Bd);
    glds16(Bp + t * 32 + hstep, Bd + 4096);
    __syncthreads();                       // staging landed (drain hidden by
                                           // co-resident blocks, m114)
    s16x8 a[4], b[4];
    #pragma unroll
    for (int i = 0; i < 4; i++) a[i] = *(const s16x8*)(((const char*)As) + offA[i]);
    #pragma unroll
    for (int j = 0; j < 4; j++) b[j] = *(const s16x8*)(((const char*)Bs) + offB[j]);
    #pragma unroll
    for (int i = 0; i < 4; i++)
      #pragma unroll
      for (int j = 0; j < 4; j++)
        acc[i][j] = __builtin_amdgcn_mfma_f32_16x16x32_bf16(a[i], b[j], acc[i][j], 0, 0, 0);
  }
}

// ------- GEMM1: [16384x768] x [5376x768]^T -> q/k/v/comb(gelu) -------
__global__ __launch_bounds__(256, 3) void gemm1_k(
    const unsigned short* __restrict__ A, const unsigned short* __restrict__ BT,
    const float* __restrict__ bias,
    unsigned short* __restrict__ qb, unsigned short* __restrict__ kb,
    unsigned short* __restrict__ vb, unsigned short* __restrict__ comb)
{
  __shared__ short As[128 * 32];
  __shared__ short Bs[128 * 32];
  const int tid = threadIdx.x, lane = tid & 63, wv = tid >> 6;
  const int quad = lane >> 4, l15 = lane & 15;
  const int wr = wv >> 1, wc = wv & 1;

  // supertile remap: GROUP_M=16 m-rows per super-row, n fastest within group
  const int nbx = gridDim.x;                    // 42
  const int bid = blockIdx.x + blockIdx.y * nbx;
  const int GM = 16;
  const int group = bid / (GM * nbx);
  const int rem   = bid % (GM * nbx);
  const int m0 = (group * GM + (rem % GM)) * 128;
  const int n0 = (rem / GM) * 128;

  f32x4 acc[4][4];
  #pragma unroll
  for (int i = 0; i < 4; i++)
    #pragma unroll
    for (int j = 0; j < 4; j++) acc[i][j] = (f32x4){0.f,0.f,0.f,0.f};

  gemm_tile128<HIDN>(A, BT, As, Bs, tid, quad, l15, wr, wc, m0, n0, acc);

  // block-uniform output class (boundaries 768/1536/2304 are multiples of 128)
  unsigned short* dstb; int cb; bool isff = false;
  if (n0 < 768)       { dstb = qb;   cb = n0; }
  else if (n0 < 1536) { dstb = kb;   cb = n0 - 768; }
  else if (n0 < 2304) { dstb = vb;   cb = n0 - 1536; }
  else                { dstb = comb; cb = n0 - 1536; isff = true; }
  const int rowstride = isff ? COMBN : HIDN;

  float bsv[4];
  #pragma unroll
  for (int nf = 0; nf < 4; nf++) bsv[nf] = bias[n0 + wc * 64 + nf * 16 + l15];

  // nf-INNER: per (mf,r) the wave writes a contiguous 128B row-run
  #pragma unroll
  for (int mf = 0; mf < 4; mf++){
    #pragma unroll
    for (int r = 0; r < 4; r++){
      const int row = m0 + wr * 64 + mf * 16 + quad * 4 + r;
      unsigned short* rp = dstb + (size_t)row * rowstride + cb + wc * 64;
      #pragma unroll
      for (int nf = 0; nf < 4; nf++){
        float val = acc[mf][nf][r] + bsv[nf];
        if (isff) val = gelu_fast(val);
        rp[nf * 16 + l15] = f2bf(val);
      }
    }
  }
}

// ------- GEMM2: [16384x3840] x [768x3840]^T + b + xn residual -> fp32 -------
__global__ __launch_bounds__(256, 3) void gemm2_k(
    const unsigned short* __restrict__ A, const unsigned short* __restrict__ BT,
    const float* __restrict__ bias, const unsigned short* __restrict__ xn,
    float* __restrict__ outp)
{
  __shared__ short As[128 * 32];
  __shared__ short Bs[128 * 32];
  const int tid = threadIdx.x, lane = tid & 63, wv = tid >> 6;
  const int quad = lane >> 4, l15 = lane & 15;
  const int wr = wv >> 1, wc = wv & 1;
  const int n0 = blockIdx.x * 128, m0 = blockIdx.y * 128;

  f32x4 acc[4][4];
  #pragma unroll
  for (int i = 0; i < 4; i++)
    #pragma unroll
    for (int j = 0; j < 4; j++) acc[i][j] = (f32x4){0.f,0.f,0.f,0.f};

  gemm_tile128<COMBN>(A, BT, As, Bs, tid, quad, l15, wr, wc, m0, n0, acc);

  float bsv[4];
  #pragma unroll
  for (int nf = 0; nf < 4; nf++) bsv[nf] = bias[n0 + wc * 64 + nf * 16 + l15];

  // nf-INNER: per (mf,r) the wave reads/writes a contiguous 256B row-run
  #pragma unroll
  for (int mf = 0; mf < 4; mf++){
    #pragma unroll
    for (int r = 0; r < 4; r++){
      const int row = m0 + wr * 64 + mf * 16 + quad * 4 + r;
      const size_t rb = (size_t)row * HIDN + n0 + wc * 64;
      #pragma unroll
      for (int nf = 0; nf < 4; nf++){
        const size_t o = rb + nf * 16 + l15;
        outp[o] = bf2f(xn[o]) + acc[mf][nf][r] + bsv[nf];
      }
    }
  }
}

// ------- pre-rotate Q (with 1/8 scale) and K in place; layout [tok][768] -------
__global__ __launch_bounds__(384) void rope_qk(
    unsigned short* __restrict__ qb, unsigned short* __restrict__ kb,
    const float* __restrict__ psin, const float* __restrict__ pcos)
{
  __shared__ float ss[2048], cs[2048];
  const int tid = threadIdx.x, g = blockIdx.x;
  #pragma unroll
  for (int rep = 0; rep < 6; rep++){
    int idx = rep * 384 + tid;
    if (idx < 2048){
      int tok = idx >> 5, p = idx & 31;
      size_t gt = ((size_t)(g * 64 + tok)) * DHD + 2 * p;
      ss[idx] = psin[gt];
      cs[idx] = pcos[gt];
    }
  }
  __syncthreads();
  const int p = tid & 31;
  unsigned* q32 = (unsigned*)qb;
  unsigned* k32 = (unsigned*)kb;
  for (int tok = 0; tok < 64; tok++){
    const size_t a = ((size_t)(g * 64 + tok)) * 384 + tid;
    const float s = ss[tok * 32 + p], c0 = cs[tok * 32 + p];
    unsigned u = q32[a];
    float e = bf2f((unsigned short)(u & 0xffff));
    float d = bf2f((unsigned short)(u >> 16));
    q32[a] = (unsigned)f2bf((e * c0 - d * s) * 0.125f)
           | (((unsigned)f2bf((d * c0 + e * s) * 0.125f)) << 16);
    u = k32[a];
    e = bf2f((unsigned short)(u & 0xffff));
    d = bf2f((unsigned short)(u >> 16));
    k32[a] = (unsigned)f2bf(e * c0 - d * s)
           | (((unsigned)f2bf(d * c0 + e * s)) << 16);
  }
}

// ------- chunked local attention: pre-roped Q/K [tok][768], 64-key tiles -------
__global__ __launch_bounds__(256) void attn_kernel(
    const unsigned short* __restrict__ qb, const unsigned short* __restrict__ kb,
    const unsigned short* __restrict__ vb, unsigned short* __restrict__ comb,
    const int* __restrict__ lenp)
{
  __shared__ short Ks[2][64 * 72];
  __shared__ short Vt[2][64 * 64];
  __shared__ short Ps[4][16 * 72];
  const int tid = threadIdx.x, lane = tid & 63, wv = tid >> 6;
  const int quad = lane >> 4, l15 = lane & 15;
  const int h = blockIdx.y, c = blockIdx.x;
  const unsigned lm = ~((unsigned)lenp[0] - 1u);
  const int i0 = c * CHUNK + wv * 64;
  const unsigned short* qh = qb + h * DHD;
  const unsigned short* kh = kb + h * DHD;
  const unsigned short* vh = vb + h * DHD;

  s16x8 qf[4][2];
  #pragma unroll
  for (int rt = 0; rt < 4; rt++){
    const unsigned short* qr = qh + (size_t)(i0 + rt * 16 + l15) * HIDN;
    qf[rt][0] = *(const s16x8*)(qr + quad * 8);
    qf[rt][1] = *(const s16x8*)(qr + 32 + quad * 8);
  }

  f32x4 O[4][4];
  float mm[4][4], ll[4][4];
  #pragma unroll
  for (int rt = 0; rt < 4; rt++)
    #pragma unroll
    for (int j = 0; j < 4; j++){ O[rt][j] = (f32x4){0,0,0,0}; mm[rt][j] = -1e30f; ll[rt][j] = 0.f; }
  short* myP = &Ps[wv][0];

  const int skey = tid & 63, sseg = tid >> 6;
  const int jb0 = c * CHUNK - 256;
  s16x8 kr[2], vr[2];

  auto issue = [&](int jb){
    if (jb >= 0){
      const unsigned short* kp = kh + (size_t)(jb + skey) * HIDN + sseg * 16;
      const unsigned short* vp = vh + (size_t)(jb + skey) * HIDN + sseg * 16;
      kr[0] = *(const s16x8*)(kp);     kr[1] = *(const s16x8*)(kp + 8);
      vr[0] = *(const s16x8*)(vp);     vr[1] = *(const s16x8*)(vp + 8);
    } else {
      kr[0] = kr[1] = vr[0] = vr[1] = (s16x8){0,0,0,0,0,0,0,0};
    }
  };

  issue(jb0);
  for (int tb = 0; tb < 8; tb++){
    const int jb = jb0 + tb * 64;
    const int buf = tb & 1;
    short* Kb = &Ks[buf][0];
    short* Vb = &Vt[buf][0];
    *(s16x8*)(Kb + skey * 72 + sseg * 16)     = kr[0];
    *(s16x8*)(Kb + skey * 72 + sseg * 16 + 8) = kr[1];
    #pragma unroll
    for (int half = 0; half < 2; half++)
      #pragma unroll
      for (int j = 0; j < 8; j++){
        const int d = sseg * 16 + half * 8 + j;
        Vb[d * 64 + (((skey & 56) ^ ((d & 7) << 3)) | (skey & 7))] = vr[half][j];
      }
    if (tb < 7) issue(jb + 64);
    __syncthreads();

    const bool act = (jb >= 0) && (jb <= i0 + 63) && (jb + 63 >= i0 - 255) &&
                     (((unsigned)i0 & lm) == ((unsigned)jb & lm));
    if (!act) continue;

    #pragma unroll
    for (int rt = 0; rt < 4; rt++){
      const int ilo = i0 + rt * 16;
      if (ilo + 15 < jb || ilo - (jb + 63) >= WIN) continue;
      f32x4 sc[4];
      #pragma unroll
      for (int ct = 0; ct < 4; ct++){
        const short* kbase = Kb + (ct * 16 + l15) * 72 + quad * 8;
        const s16x8 b0 = *(const s16x8*)(kbase);
        const s16x8 b1 = *(const s16x8*)(kbase + 32);
        f32x4 aa = (f32x4){0,0,0,0};
        aa = __builtin_amdgcn_mfma_f32_16x16x32_bf16(qf[rt][0], b0, aa, 0, 0, 0);
        aa = __builtin_amdgcn_mfma_f32_16x16x32_bf16(qf[rt][1], b1, aa, 0, 0, 0);
        sc[ct] = aa;
      }
      float alph[4];
      #pragma unroll
      for (int r = 0; r < 4; r++){
        const int i = ilo + quad * 4 + r;
        #pragma unroll
        for (int ct = 0; ct < 4; ct++){
          const unsigned dd = (unsigned)(i - (jb + ct * 16 + l15));
          if (dd >= 256u) sc[ct][r] = -1e30f;
        }
        float mx = fmaxf(fmaxf(sc[0][r], sc[1][r]), fmaxf(sc[2][r], sc[3][r]));
        mx = fmaxf(mx, __shfl_xor(mx, 1));
        mx = fmaxf(mx, __shfl_xor(mx, 2));
        mx = fmaxf(mx, __shfl_xor(mx, 4));
        mx = fmaxf(mx, __shfl_xor(mx, 8));
        const float mnew = fmaxf(mm[rt][r], mx);
        alph[r] = __expf(mm[rt][r] - mnew);
        mm[rt][r] = mnew;
        float p0 = __expf(sc[0][r] - mnew);
        float p1 = __expf(sc[1][r] - mnew);
        float p2 = __expf(sc[2][r] - mnew);
        float p3 = __expf(sc[3][r] - mnew);
        sc[0][r] = p0; sc[1][r] = p1; sc[2][r] = p2; sc[3][r] = p3;
        float rsum = (p0 + p1) + (p2 + p3);
        rsum += __shfl_xor(rsum, 1);
        rsum += __shfl_xor(rsum, 2);
        rsum += __shfl_xor(rsum, 4);
        rsum += __shfl_xor(rsum, 8);
        ll[rt][r] = ll[rt][r] * alph[r] + rsum;
      }
      #pragma unroll
      for (int co = 0; co < 4; co++)
        #pragma unroll
        for (int r = 0; r < 4; r++) O[rt][co][r] *= alph[r];
      #pragma unroll
      for (int r = 0; r < 4; r++){
        const int prow = quad * 4 + r;
        #pragma unroll
        for (int ct = 0; ct < 4; ct++)
          myP[prow * 72 + ct * 16 + l15] = (short)f2bf(sc[ct][r]);
      }
      #pragma unroll
      for (int ks2 = 0; ks2 < 2; ks2++){
        const s16x8 pf = *(const s16x8*)(myP + l15 * 72 + ks2 * 32 + quad * 8);
        #pragma unroll
        for (int co = 0; co < 4; co++){
          const int d = co * 16 + l15;
          const s16x8 vf = *(const s16x8*)(Vb + d * 64 +
                              ((ks2 * 32 + quad * 8) ^ ((d & 7) << 3)));
          O[rt][co] = __builtin_amdgcn_mfma_f32_16x16x32_bf16(pf, vf, O[rt][co], 0, 0, 0);
        }
      }
    }
  }

  #pragma unroll
  for (int rt = 0; rt < 4; rt++)
    #pragma unroll
    for (int co = 0; co < 4; co++)
      #pragma unroll
      for (int r = 0; r < 4; r++){
        const int tok = i0 + rt * 16 + quad * 4 + r;
        comb[(size_t)tok * COMBN + h * DHD + co * 16 + l15] = f2bf(O[rt][co][r] / ll[rt][r]);
      }
}

extern "C" void kernel_launch(void* const* d_in, const int* in_sizes, int n_in,
                              void* d_out, int out_size, void* d_ws, size_t ws_size,
                              hipStream_t stream)
{
  const float* x     = (const float*)d_in[0];
  const float* psin  = (const float*)d_in[2];
  const float* pcos  = (const float*)d_in[3];
  const float* lns   = (const float*)d_in[4];
  const float* lno   = (const float*)d_in[5];
  const float* w_in  = (const float*)d_in[6];
  const float* b_in  = (const float*)d_in[7];
  const float* w_out = (const float*)d_in[8];
  const float* b_out = (const float*)d_in[9];
  const int*   lenp  = (const int*)d_in[10];
  float* out = (float*)d_out;

  char* ws = (char*)d_ws;
  size_t off = 0;
  unsigned short* xn    = (unsigned short*)(ws + off); off += (size_t)N_TOK * HIDN * 2;
  unsigned short* wInT  = (unsigned short*)(ws + off); off += (size_t)MIDN * HIDN * 2;
  unsigned short* wOutT = (unsigned short*)(ws + off); off += (size_t)HIDN * COMBN * 2;
  unsigned short* qbuf  = (unsigned short*)(ws + off); off += (size_t)N_TOK * HIDN * 2;
  unsigned short* kbuf  = (unsigned short*)(ws + off); off += (size_t)N_TOK * HIDN * 2;
  unsigned short* vbuf  = (unsigned short*)(ws + off); off += (size_t)N_TOK * HIDN * 2;
  unsigned short* comb  = (unsigned short*)(ws + off); off += (size_t)N_TOK * COMBN * 2;

  transpose_f2b<<<dim3(MIDN/64, HIDN/64), 256, 0, stream>>>(w_in, wInT, HIDN, MIDN);
  transpose_f2b<<<dim3(HIDN/64, COMBN/64), 256, 0, stream>>>(w_out, wOutT, COMBN, HIDN);
  ln_kernel<<<dim3(N_TOK/4), 256, 0, stream>>>(x, lns, lno, xn);
  gemm1_k<<<dim3(MIDN/128, N_TOK/128), 256, 0, stream>>>(
      xn, wInT, b_in, qbuf, kbuf, vbuf, comb);
  rope_qk<<<dim3(N_TOK/64), 384, 0, stream>>>(qbuf, kbuf, psin, pcos);
  attn_kernel<<<dim3(N_TOK/CHUNK, NH), 256, 0, stream>>>(
      qbuf, kbuf, vbuf, comb, lenp);
  gemm2_k<<<dim3(HIDN/128, N_TOK/128), 256, 0, stream>>>(
      comb, wOutT, b_out, xn, out);
}

// Round 8
// 613.740 us; speedup vs baseline: 1.2250x; 1.0211x over previous
//
#include <hip/hip_runtime.h>

#define N_TOK 16384
#define HIDN  768
#define MIDN  5376
#define COMBN 3840
#define NH    12
#define DHD   64
#define CHUNK 256
#define WIN   256

typedef short s16x8 __attribute__((ext_vector_type(8)));
typedef short s16x4 __attribute__((ext_vector_type(4)));
typedef float f32x4 __attribute__((ext_vector_type(4)));

__device__ __forceinline__ float bf2f(unsigned short u){
  union { unsigned u; float f; } x; x.u = ((unsigned)u) << 16; return x.f;
}
__device__ __forceinline__ unsigned short f2bf(float f){
  union { float f; unsigned u; } x; x.f = f;
  unsigned r = x.u + 0x7fffu + ((x.u >> 16) & 1u);
  return (unsigned short)(r >> 16);
}
__device__ __forceinline__ float gelu_fast(float x){
  float u = -1.5957691216057308f * (x + 0.044715f * x * x * x);
  return x / (1.f + __expf(u));
}
__device__ __forceinline__ void glds16(const void* g, void* l){
  __builtin_amdgcn_global_load_lds(
      (const __attribute__((address_space(1))) unsigned*)g,
      (__attribute__((address_space(3))) unsigned*)l, 16, 0, 0);
}

// ------- transpose + downcast: in fp32 [R][Cc] -> out bf16 [Cc][R] -------
__global__ __launch_bounds__(256) void transpose_f2b(
    const float* __restrict__ in, unsigned short* __restrict__ out,
    int R, int Cc)
{
  __shared__ short t[64 * 72];
  const int tid = threadIdx.x;
  const int r0 = blockIdx.y * 64, c0 = blockIdx.x * 64;
  #pragma unroll
  for (int rep = 0; rep < 4; rep++){
    int v = tid + 256 * rep;
    int r = v >> 4, s = v & 15;
    float4 d = *(const float4*)(in + (size_t)(r0 + r) * Cc + c0 + s * 4);
    s16x4 o = { (short)f2bf(d.x), (short)f2bf(d.y), (short)f2bf(d.z), (short)f2bf(d.w) };
    *(s16x4*)(t + r * 72 + s * 4) = o;
  }
  __syncthreads();
  #pragma unroll
  for (int rep = 0; rep < 2; rep++){
    int v = tid + 256 * rep;
    int c = v & 63, s2 = v >> 6;
    s16x8 d;
    #pragma unroll
    for (int j = 0; j < 8; j++) d[j] = t[(s2 * 8 + j) * 72 + c];
    *(s16x8*)(out + (size_t)(c0 + c) * R + r0 + s2 * 8) = d;
  }
}

// ------- layernorm: fp32 in -> bf16 out, one wave per row -------
__global__ __launch_bounds__(256) void ln_kernel(
    const float* __restrict__ x, const float* __restrict__ sc,
    const float* __restrict__ ofs, unsigned short* __restrict__ xn)
{
  const int lane = threadIdx.x & 63, wv = threadIdx.x >> 6;
  const int row = blockIdx.x * 4 + wv;
  const float4* xr = (const float4*)(x + (size_t)row * HIDN);
  float4 vals[3];
  float sum = 0.f, sq = 0.f;
  #pragma unroll
  for (int j = 0; j < 3; j++){
    vals[j] = xr[lane + 64 * j];
    sum += vals[j].x + vals[j].y + vals[j].z + vals[j].w;
    sq  += vals[j].x * vals[j].x + vals[j].y * vals[j].y
         + vals[j].z * vals[j].z + vals[j].w * vals[j].w;
  }
  #pragma unroll
  for (int o = 1; o < 64; o <<= 1){ sum += __shfl_xor(sum, o); sq += __shfl_xor(sq, o); }
  const float mu = sum * (1.f / HIDN);
  const float rs = rsqrtf(fmaxf(sq * (1.f / HIDN) - mu * mu, 0.f) + 1e-5f);
  s16x4* xo = (s16x4*)(xn + (size_t)row * HIDN);
  const float4* scp = (const float4*)sc;
  const float4* ofp = (const float4*)ofs;
  #pragma unroll
  for (int j = 0; j < 3; j++){
    int p = lane + 64 * j;
    float4 s = scp[p], o = ofp[p];
    s16x4 w;
    w[0] = (short)f2bf((vals[j].x - mu) * rs * s.x + o.x);
    w[1] = (short)f2bf((vals[j].y - mu) * rs * s.y + o.y);
    w[2] = (short)f2bf((vals[j].z - mu) * rs * s.z + o.z);
    w[3] = (short)f2bf((vals[j].w - mu) * rs * s.w + o.w);
    xo[p] = w;
  }
}

// ============================================================================
// R8 GEMM: 128x128 tile, 256 threads = 4 waves (2Mx2N), acc[4][4]; BK=64,
// 2 LDS buffers split by K-HALF (khalf = 128 rows x 32 K, stored contiguous),
// 2 phases per K-tile, counted vmcnt, 1 barrier/phase, ds_read-ahead.
//
// LDS bytes: buf b at b*32768; A khalf kh at +kh*8192; B at +16384+kh*8192.
// Total 64 KiB -> 2 blocks/CU.  Swizzle (verified R6/R7, conflicts=0):
// 64B row = 4 segs of 16B, phys seg = seg ^ ((row>>1)&3); glds16 dest linear,
// inverse swizzle on GLOBAL source col: ksw = ((tid&3)^((tid>>3)&3))*8 elems.
//
// Phase (t, kh):
//   stage khalf kh of tile t+1 into buf^1 (4 glds16)   [WAR-safe: that region
//     was last ds_read >=2 barriers ago]
//   16 MFMA on pre-read frags (setprio-wrapped)
//   s_waitcnt vmcnt(4)   [waits ONLY the khalf staged 2 phases ago; the 4
//     loads just issued + nothing else remain in flight -- never drains]
//   s_barrier            [the only barrier in the phase]
//   ds_read next phase's 8 frags (consumed after next phase's MFMA issue,
//     i.e. a full cluster ahead; compiler inserts the lgkmcnt)
// ============================================================================
template<int K>
__device__ __forceinline__ void gemm_pipe2(
    const unsigned short* __restrict__ A, const unsigned short* __restrict__ BT,
    short* SM,   // 32768 shorts = 64 KiB
    int tid, int quad, int l15, int wr, int wc, int m0, int n0,
    f32x4 acc[4][4])
{
  constexpr int T = K / 64;
  char* const SMc = (char*)SM;
  const int srow = tid >> 2;
  const int ksw  = ((tid & 3) ^ ((tid >> 3) & 3)) * 8;
  const unsigned short* Ap = A  + (size_t)(m0 + srow) * K + ksw;
  const unsigned short* Bp = BT + (size_t)(n0 + srow) * K + ksw;
  const size_t rstep = (size_t)64 * K;

  const int segx = ((quad ^ ((l15 >> 1) & 3)) << 4);
  int offA[4], offB[4];
  #pragma unroll
  for (int mf = 0; mf < 4; mf++) offA[mf] = (wr * 64 + mf * 16 + l15) * 64 + segx;
  #pragma unroll
  for (int nf = 0; nf < 4; nf++) offB[nf] = (wc * 64 + nf * 16 + l15) * 64 + segx;

  auto stage = [&](int tt, int kh, int b){
    const int coff = tt * 64 + kh * 32;
    char* Ad = SMc + b * 32768 + kh * 8192 + tid * 16;
    char* Bd = SMc + b * 32768 + 16384 + kh * 8192 + tid * 16;
    glds16(Ap + coff,         Ad);
    glds16(Ap + coff + rstep, Ad + 4096);
    glds16(Bp + coff,         Bd);
    glds16(Bp + coff + rstep, Bd + 4096);
  };

  s16x8 af[4], bf[4];
  auto rdfrags = [&](int b, int kh){
    const char* Ab = SMc + b * 32768 + kh * 8192;
    const char* Bb = SMc + b * 32768 + 16384 + kh * 8192;
    #pragma unroll
    for (int i = 0; i < 4; i++) af[i] = *(const s16x8*)(Ab + offA[i]);
    #pragma unroll
    for (int j = 0; j < 4; j++) bf[j] = *(const s16x8*)(Bb + offB[j]);
  };

  // prologue: stage both khalves of tile 0; wait khalf0; read its frags
  stage(0, 0, 0);
  stage(0, 1, 0);
  asm volatile("s_waitcnt vmcnt(4)" ::: "memory");
  asm volatile("s_barrier" ::: "memory");
  rdfrags(0, 0);

  for (int t = 0; t < T; ++t){
    const int cur = t & 1;
    // ---- phase 0 (khalf 0 of tile t) ----
    if (t + 1 < T) stage(t + 1, 0, cur ^ 1);
    __builtin_amdgcn_s_setprio(1);
    #pragma unroll
    for (int i = 0; i < 4; i++)
      #pragma unroll
      for (int j = 0; j < 4; j++)
        acc[i][j] = __builtin_amdgcn_mfma_f32_16x16x32_bf16(af[i], bf[j], acc[i][j], 0, 0, 0);
    __builtin_amdgcn_s_setprio(0);
    if (t + 1 < T){ asm volatile("s_waitcnt vmcnt(4)" ::: "memory"); }
    else          { asm volatile("s_waitcnt vmcnt(0)" ::: "memory"); }
    asm volatile("s_barrier" ::: "memory");
    rdfrags(cur, 1);
    // ---- phase 1 (khalf 1 of tile t) ----
    if (t + 1 < T) stage(t + 1, 1, cur ^ 1);
    __builtin_amdgcn_s_setprio(1);
    #pragma unroll
    for (int i = 0; i < 4; i++)
      #pragma unroll
      for (int j = 0; j < 4; j++)
        acc[i][j] = __builtin_amdgcn_mfma_f32_16x16x32_bf16(af[i], bf[j], acc[i][j], 0, 0, 0);
    __builtin_amdgcn_s_setprio(0);
    if (t + 1 < T){
      asm volatile("s_waitcnt vmcnt(4)" ::: "memory");
      asm volatile("s_barrier" ::: "memory");
      rdfrags(cur ^ 1, 0);
    }
  }
}

// ------- GEMM1: [16384x768] x [5376x768]^T -> q/k/v/comb(gelu) -------
__global__ __launch_bounds__(256, 2) void gemm1_k(
    const unsigned short* __restrict__ A, const unsigned short* __restrict__ BT,
    const float* __restrict__ bias,
    unsigned short* __restrict__ qb, unsigned short* __restrict__ kb,
    unsigned short* __restrict__ vb, unsigned short* __restrict__ comb)
{
  __shared__ short SM[32768];
  const int tid = threadIdx.x, lane = tid & 63, wv = tid >> 6;
  const int quad = lane >> 4, l15 = lane & 15;
  const int wr = wv >> 1, wc = wv & 1;

  // supertile remap: GROUP_M=16 m-rows per super-row, m fastest within group
  const int nbx = gridDim.x;                    // 42
  const int bid = blockIdx.x + blockIdx.y * nbx;
  const int GM = 16;
  const int group = bid / (GM * nbx);
  const int rem   = bid % (GM * nbx);
  const int m0 = (group * GM + (rem % GM)) * 128;
  const int n0 = (rem / GM) * 128;

  f32x4 acc[4][4];
  #pragma unroll
  for (int i = 0; i < 4; i++)
    #pragma unroll
    for (int j = 0; j < 4; j++) acc[i][j] = (f32x4){0.f,0.f,0.f,0.f};

  gemm_pipe2<HIDN>(A, BT, SM, tid, quad, l15, wr, wc, m0, n0, acc);

  // block-uniform output class (boundaries 768/1536/2304 are multiples of 128)
  unsigned short* dstb; int cb; bool isff = false;
  if (n0 < 768)       { dstb = qb;   cb = n0; }
  else if (n0 < 1536) { dstb = kb;   cb = n0 - 768; }
  else if (n0 < 2304) { dstb = vb;   cb = n0 - 1536; }
  else                { dstb = comb; cb = n0 - 1536; isff = true; }
  const int rowstride = isff ? COMBN : HIDN;

  float bsv[4];
  #pragma unroll
  for (int nf = 0; nf < 4; nf++) bsv[nf] = bias[n0 + wc * 64 + nf * 16 + l15];

  // nf-INNER: per (mf,r) the wave writes a contiguous 128B row-run
  #pragma unroll
  for (int mf = 0; mf < 4; mf++){
    #pragma unroll
    for (int r = 0; r < 4; r++){
      const int row = m0 + wr * 64 + mf * 16 + quad * 4 + r;
      unsigned short* rp = dstb + (size_t)row * rowstride + cb + wc * 64;
      #pragma unroll
      for (int nf = 0; nf < 4; nf++){
        float val = acc[mf][nf][r] + bsv[nf];
        if (isff) val = gelu_fast(val);
        rp[nf * 16 + l15] = f2bf(val);
      }
    }
  }
}

// ------- GEMM2: [16384x3840] x [768x3840]^T + b + xn residual -> fp32 -------
__global__ __launch_bounds__(256, 2) void gemm2_k(
    const unsigned short* __restrict__ A, const unsigned short* __restrict__ BT,
    const float* __restrict__ bias, const unsigned short* __restrict__ xn,
    float* __restrict__ outp)
{
  __shared__ short SM[32768];
  const int tid = threadIdx.x, lane = tid & 63, wv = tid >> 6;
  const int quad = lane >> 4, l15 = lane & 15;
  const int wr = wv >> 1, wc = wv & 1;
  const int n0 = blockIdx.x * 128, m0 = blockIdx.y * 128;

  f32x4 acc[4][4];
  #pragma unroll
  for (int i = 0; i < 4; i++)
    #pragma unroll
    for (int j = 0; j < 4; j++) acc[i][j] = (f32x4){0.f,0.f,0.f,0.f};

  gemm_pipe2<COMBN>(A, BT, SM, tid, quad, l15, wr, wc, m0, n0, acc);

  float bsv[4];
  #pragma unroll
  for (int nf = 0; nf < 4; nf++) bsv[nf] = bias[n0 + wc * 64 + nf * 16 + l15];

  // nf-INNER: per (mf,r) the wave reads/writes a contiguous 256B row-run
  #pragma unroll
  for (int mf = 0; mf < 4; mf++){
    #pragma unroll
    for (int r = 0; r < 4; r++){
      const int row = m0 + wr * 64 + mf * 16 + quad * 4 + r;
      const size_t rb = (size_t)row * HIDN + n0 + wc * 64;
      #pragma unroll
      for (int nf = 0; nf < 4; nf++){
        const size_t o = rb + nf * 16 + l15;
        outp[o] = bf2f(xn[o]) + acc[mf][nf][r] + bsv[nf];
      }
    }
  }
}

// ------- pre-rotate Q (with 1/8 scale) and K in place; layout [tok][768] -------
__global__ __launch_bounds__(384) void rope_qk(
    unsigned short* __restrict__ qb, unsigned short* __restrict__ kb,
    const float* __restrict__ psin, const float* __restrict__ pcos)
{
  __shared__ float ss[2048], cs[2048];
  const int tid = threadIdx.x, g = blockIdx.x;
  #pragma unroll
  for (int rep = 0; rep < 6; rep++){
    int idx = rep * 384 + tid;
    if (idx < 2048){
      int tok = idx >> 5, p = idx & 31;
      size_t gt = ((size_t)(g * 64 + tok)) * DHD + 2 * p;
      ss[idx] = psin[gt];
      cs[idx] = pcos[gt];
    }
  }
  __syncthreads();
  const int p = tid & 31;
  unsigned* q32 = (unsigned*)qb;
  unsigned* k32 = (unsigned*)kb;
  for (int tok = 0; tok < 64; tok++){
    const size_t a = ((size_t)(g * 64 + tok)) * 384 + tid;
    const float s = ss[tok * 32 + p], c0 = cs[tok * 32 + p];
    unsigned u = q32[a];
    float e = bf2f((unsigned short)(u & 0xffff));
    float d = bf2f((unsigned short)(u >> 16));
    q32[a] = (unsigned)f2bf((e * c0 - d * s) * 0.125f)
           | (((unsigned)f2bf((d * c0 + e * s) * 0.125f)) << 16);
    u = k32[a];
    e = bf2f((unsigned short)(u & 0xffff));
    d = bf2f((unsigned short)(u >> 16));
    k32[a] = (unsigned)f2bf(e * c0 - d * s)
           | (((unsigned)f2bf(d * c0 + e * s)) << 16);
  }
}

// ------- chunked local attention: pre-roped Q/K [tok][768], 64-key tiles -------
__global__ __launch_bounds__(256) void attn_kernel(
    const unsigned short* __restrict__ qb, const unsigned short* __restrict__ kb,
    const unsigned short* __restrict__ vb, unsigned short* __restrict__ comb,
    const int* __restrict__ lenp)
{
  __shared__ short Ks[2][64 * 72];
  __shared__ short Vt[2][64 * 64];
  __shared__ short Ps[4][16 * 72];
  const int tid = threadIdx.x, lane = tid & 63, wv = tid >> 6;
  const int quad = lane >> 4, l15 = lane & 15;
  const int h = blockIdx.y, c = blockIdx.x;
  const unsigned lm = ~((unsigned)lenp[0] - 1u);
  const int i0 = c * CHUNK + wv * 64;
  const unsigned short* qh = qb + h * DHD;
  const unsigned short* kh = kb + h * DHD;
  const unsigned short* vh = vb + h * DHD;

  s16x8 qf[4][2];
  #pragma unroll
  for (int rt = 0; rt < 4; rt++){
    const unsigned short* qr = qh + (size_t)(i0 + rt * 16 + l15) * HIDN;
    qf[rt][0] = *(const s16x8*)(qr + quad * 8);
    qf[rt][1] = *(const s16x8*)(qr + 32 + quad * 8);
  }

  f32x4 O[4][4];
  float mm[4][4], ll[4][4];
  #pragma unroll
  for (int rt = 0; rt < 4; rt++)
    #pragma unroll
    for (int j = 0; j < 4; j++){ O[rt][j] = (f32x4){0,0,0,0}; mm[rt][j] = -1e30f; ll[rt][j] = 0.f; }
  short* myP = &Ps[wv][0];

  const int skey = tid & 63, sseg = tid >> 6;
  const int jb0 = c * CHUNK - 256;
  s16x8 kr[2], vr[2];

  auto issue = [&](int jb){
    if (jb >= 0){
      const unsigned short* kp = kh + (size_t)(jb + skey) * HIDN + sseg * 16;
      const unsigned short* vp = vh + (size_t)(jb + skey) * HIDN + sseg * 16;
      kr[0] = *(const s16x8*)(kp);     kr[1] = *(const s16x8*)(kp + 8);
      vr[0] = *(const s16x8*)(vp);     vr[1] = *(const s16x8*)(vp + 8);
    } else {
      kr[0] = kr[1] = vr[0] = vr[1] = (s16x8){0,0,0,0,0,0,0,0};
    }
  };

  issue(jb0);
  for (int tb = 0; tb < 8; tb++){
    const int jb = jb0 + tb * 64;
    const int buf = tb & 1;
    short* Kb = &Ks[buf][0];
    short* Vb = &Vt[buf][0];
    *(s16x8*)(Kb + skey * 72 + sseg * 16)     = kr[0];
    *(s16x8*)(Kb + skey * 72 + sseg * 16 + 8) = kr[1];
    #pragma unroll
    for (int half = 0; half < 2; half++)
      #pragma unroll
      for (int j = 0; j < 8; j++){
        const int d = sseg * 16 + half * 8 + j;
        Vb[d * 64 + (((skey & 56) ^ ((d & 7) << 3)) | (skey & 7))] = vr[half][j];
      }
    if (tb < 7) issue(jb + 64);
    __syncthreads();

    const bool act = (jb >= 0) && (jb <= i0 + 63) && (jb + 63 >= i0 - 255) &&
                     (((unsigned)i0 & lm) == ((unsigned)jb & lm));
    if (!act) continue;

    #pragma unroll
    for (int rt = 0; rt < 4; rt++){
      const int ilo = i0 + rt * 16;
      if (ilo + 15 < jb || ilo - (jb + 63) >= WIN) continue;
      f32x4 sc[4];
      #pragma unroll
      for (int ct = 0; ct < 4; ct++){
        const short* kbase = Kb + (ct * 16 + l15) * 72 + quad * 8;
        const s16x8 b0 = *(const s16x8*)(kbase);
        const s16x8 b1 = *(const s16x8*)(kbase + 32);
        f32x4 aa = (f32x4){0,0,0,0};
        aa = __builtin_amdgcn_mfma_f32_16x16x32_bf16(qf[rt][0], b0, aa, 0, 0, 0);
        aa = __builtin_amdgcn_mfma_f32_16x16x32_bf16(qf[rt][1], b1, aa, 0, 0, 0);
        sc[ct] = aa;
      }
      float alph[4];
      #pragma unroll
      for (int r = 0; r < 4; r++){
        const int i = ilo + quad * 4 + r;
        #pragma unroll
        for (int ct = 0; ct < 4; ct++){
          const unsigned dd = (unsigned)(i - (jb + ct * 16 + l15));
          if (dd >= 256u) sc[ct][r] = -1e30f;
        }
        float mx = fmaxf(fmaxf(sc[0][r], sc[1][r]), fmaxf(sc[2][r], sc[3][r]));
        mx = fmaxf(mx, __shfl_xor(mx, 1));
        mx = fmaxf(mx, __shfl_xor(mx, 2));
        mx = fmaxf(mx, __shfl_xor(mx, 4));
        mx = fmaxf(mx, __shfl_xor(mx, 8));
        const float mnew = fmaxf(mm[rt][r], mx);
        alph[r] = __expf(mm[rt][r] - mnew);
        mm[rt][r] = mnew;
        float p0 = __expf(sc[0][r] - mnew);
        float p1 = __expf(sc[1][r] - mnew);
        float p2 = __expf(sc[2][r] - mnew);
        float p3 = __expf(sc[3][r] - mnew);
        sc[0][r] = p0; sc[1][r] = p1; sc[2][r] = p2; sc[3][r] = p3;
        float rsum = (p0 + p1) + (p2 + p3);
        rsum += __shfl_xor(rsum, 1);
        rsum += __shfl_xor(rsum, 2);
        rsum += __shfl_xor(rsum, 4);
        rsum += __shfl_xor(rsum, 8);
        ll[rt][r] = ll[rt][r] * alph[r] + rsum;
      }
      #pragma unroll
      for (int co = 0; co < 4; co++)
        #pragma unroll
        for (int r = 0; r < 4; r++) O[rt][co][r] *= alph[r];
      #pragma unroll
      for (int r = 0; r < 4; r++){
        const int prow = quad * 4 + r;
        #pragma unroll
        for (int ct = 0; ct < 4; ct++)
          myP[prow * 72 + ct * 16 + l15] = (short)f2bf(sc[ct][r]);
      }
      #pragma unroll
      for (int ks2 = 0; ks2 < 2; ks2++){
        const s16x8 pf = *(const s16x8*)(myP + l15 * 72 + ks2 * 32 + quad * 8);
        #pragma unroll
        for (int co = 0; co < 4; co++){
          const int d = co * 16 + l15;
          const s16x8 vf = *(const s16x8*)(Vb + d * 64 +
                              ((ks2 * 32 + quad * 8) ^ ((d & 7) << 3)));
          O[rt][co] = __builtin_amdgcn_mfma_f32_16x16x32_bf16(pf, vf, O[rt][co], 0, 0, 0);
        }
      }
    }
  }

  #pragma unroll
  for (int rt = 0; rt < 4; rt++)
    #pragma unroll
    for (int co = 0; co < 4; co++)
      #pragma unroll
      for (int r = 0; r < 4; r++){
        const int tok = i0 + rt * 16 + quad * 4 + r;
        comb[(size_t)tok * COMBN + h * DHD + co * 16 + l15] = f2bf(O[rt][co][r] / ll[rt][r]);
      }
}

extern "C" void kernel_launch(void* const* d_in, const int* in_sizes, int n_in,
                              void* d_out, int out_size, void* d_ws, size_t ws_size,
                              hipStream_t stream)
{
  const float* x     = (const float*)d_in[0];
  const float* psin  = (const float*)d_in[2];
  const float* pcos  = (const float*)d_in[3];
  const float* lns   = (const float*)d_in[4];
  const float* lno   = (const float*)d_in[5];
  const float* w_in  = (const float*)d_in[6];
  const float* b_in  = (const float*)d_in[7];
  const float* w_out = (const float*)d_in[8];
  const float* b_out = (const float*)d_in[9];
  const int*   lenp  = (const int*)d_in[10];
  float* out = (float*)d_out;

  char* ws = (char*)d_ws;
  size_t off = 0;
  unsigned short* xn    = (unsigned short*)(ws + off); off += (size_t)N_TOK * HIDN * 2;
  unsigned short* wInT  = (unsigned short*)(ws + off); off += (size_t)MIDN * HIDN * 2;
  unsigned short* wOutT = (unsigned short*)(ws + off); off += (size_t)HIDN * COMBN * 2;
  unsigned short* qbuf  = (unsigned short*)(ws + off); off += (size_t)N_TOK * HIDN * 2;
  unsigned short* kbuf  = (unsigned short*)(ws + off); off += (size_t)N_TOK * HIDN * 2;
  unsigned short* vbuf  = (unsigned short*)(ws + off); off += (size_t)N_TOK * HIDN * 2;
  unsigned short* comb  = (unsigned short*)(ws + off); off += (size_t)N_TOK * COMBN * 2;

  transpose_f2b<<<dim3(MIDN/64, HIDN/64), 256, 0, stream>>>(w_in, wInT, HIDN, MIDN);
  transpose_f2b<<<dim3(HIDN/64, COMBN/64), 256, 0, stream>>>(w_out, wOutT, COMBN, HIDN);
  ln_kernel<<<dim3(N_TOK/4), 256, 0, stream>>>(x, lns, lno, xn);
  gemm1_k<<<dim3(MIDN/128, N_TOK/128), 256, 0, stream>>>(
      xn, wInT, b_in, qbuf, kbuf, vbuf, comb);
  rope_qk<<<dim3(N_TOK/64), 384, 0, stream>>>(qbuf, kbuf, psin, pcos);
  attn_kernel<<<dim3(N_TOK/CHUNK, NH), 256, 0, stream>>>(
      qbuf, kbuf, vbuf, comb, lenp);
  gemm2_k<<<dim3(HIDN/128, N_TOK/128), 256, 0, stream>>>(
      comb, wOutT, b_out, xn, out);
}

// Round 9
// 608.247 us; speedup vs baseline: 1.2361x; 1.0090x over previous
//
#include <hip/hip_runtime.h>

#define N_TOK 16384
#define HIDN  768
#define MIDN  5376
#define COMBN 3840
#define NH    12
#define DHD   64
#define CHUNK 256
#define WIN   256

typedef short s16x8 __attribute__((ext_vector_type(8)));
typedef short s16x4 __attribute__((ext_vector_type(4)));
typedef float f32x4 __attribute__((ext_vector_type(4)));

__device__ __forceinline__ float bf2f(unsigned short u){
  union { unsigned u; float f; } x; x.u = ((unsigned)u) << 16; return x.f;
}
__device__ __forceinline__ unsigned short f2bf(float f){
  union { float f; unsigned u; } x; x.f = f;
  unsigned r = x.u + 0x7fffu + ((x.u >> 16) & 1u);
  return (unsigned short)(r >> 16);
}
__device__ __forceinline__ float gelu_fast(float x){
  float u = -1.5957691216057308f * (x + 0.044715f * x * x * x);
  return x / (1.f + __expf(u));
}
__device__ __forceinline__ void glds16(const void* g, void* l){
  __builtin_amdgcn_global_load_lds(
      (const __attribute__((address_space(1))) unsigned*)g,
      (__attribute__((address_space(3))) unsigned*)l, 16, 0, 0);
}

// ------- transpose + downcast: in fp32 [R][Cc] -> out bf16 [Cc][R] -------
__global__ __launch_bounds__(256) void transpose_f2b(
    const float* __restrict__ in, unsigned short* __restrict__ out,
    int R, int Cc)
{
  __shared__ short t[64 * 72];
  const int tid = threadIdx.x;
  const int r0 = blockIdx.y * 64, c0 = blockIdx.x * 64;
  #pragma unroll
  for (int rep = 0; rep < 4; rep++){
    int v = tid + 256 * rep;
    int r = v >> 4, s = v & 15;
    float4 d = *(const float4*)(in + (size_t)(r0 + r) * Cc + c0 + s * 4);
    s16x4 o = { (short)f2bf(d.x), (short)f2bf(d.y), (short)f2bf(d.z), (short)f2bf(d.w) };
    *(s16x4*)(t + r * 72 + s * 4) = o;
  }
  __syncthreads();
  #pragma unroll
  for (int rep = 0; rep < 2; rep++){
    int v = tid + 256 * rep;
    int c = v & 63, s2 = v >> 6;
    s16x8 d;
    #pragma unroll
    for (int j = 0; j < 8; j++) d[j] = t[(s2 * 8 + j) * 72 + c];
    *(s16x8*)(out + (size_t)(c0 + c) * R + r0 + s2 * 8) = d;
  }
}

// ------- layernorm: fp32 in -> bf16 out, one wave per row -------
__global__ __launch_bounds__(256) void ln_kernel(
    const float* __restrict__ x, const float* __restrict__ sc,
    const float* __restrict__ ofs, unsigned short* __restrict__ xn)
{
  const int lane = threadIdx.x & 63, wv = threadIdx.x >> 6;
  const int row = blockIdx.x * 4 + wv;
  const float4* xr = (const float4*)(x + (size_t)row * HIDN);
  float4 vals[3];
  float sum = 0.f, sq = 0.f;
  #pragma unroll
  for (int j = 0; j < 3; j++){
    vals[j] = xr[lane + 64 * j];
    sum += vals[j].x + vals[j].y + vals[j].z + vals[j].w;
    sq  += vals[j].x * vals[j].x + vals[j].y * vals[j].y
         + vals[j].z * vals[j].z + vals[j].w * vals[j].w;
  }
  #pragma unroll
  for (int o = 1; o < 64; o <<= 1){ sum += __shfl_xor(sum, o); sq += __shfl_xor(sq, o); }
  const float mu = sum * (1.f / HIDN);
  const float rs = rsqrtf(fmaxf(sq * (1.f / HIDN) - mu * mu, 0.f) + 1e-5f);
  s16x4* xo = (s16x4*)(xn + (size_t)row * HIDN);
  const float4* scp = (const float4*)sc;
  const float4* ofp = (const float4*)ofs;
  #pragma unroll
  for (int j = 0; j < 3; j++){
    int p = lane + 64 * j;
    float4 s = scp[p], o = ofp[p];
    s16x4 w;
    w[0] = (short)f2bf((vals[j].x - mu) * rs * s.x + o.x);
    w[1] = (short)f2bf((vals[j].y - mu) * rs * s.y + o.y);
    w[2] = (short)f2bf((vals[j].z - mu) * rs * s.z + o.z);
    w[3] = (short)f2bf((vals[j].w - mu) * rs * s.w + o.w);
    xo[p] = w;
  }
}

// ============================================================================
// R9 GEMM K-loop: unchanged from R8 (verified). 128x128 tile, 256 threads =
// 4 waves (2Mx2N), acc[4][4]; BK=64, 2 LDS buffers split by K-half, 2 phases
// per K-tile, counted vmcnt(4), 1 barrier/phase, ds_read-ahead. 64 KiB LDS.
// ============================================================================
template<int K>
__device__ __forceinline__ void gemm_pipe2(
    const unsigned short* __restrict__ A, const unsigned short* __restrict__ BT,
    short* SM,   // 32768 shorts = 64 KiB
    int tid, int quad, int l15, int wr, int wc, int m0, int n0,
    f32x4 acc[4][4])
{
  constexpr int T = K / 64;
  char* const SMc = (char*)SM;
  const int srow = tid >> 2;
  const int ksw  = ((tid & 3) ^ ((tid >> 3) & 3)) * 8;
  const unsigned short* Ap = A  + (size_t)(m0 + srow) * K + ksw;
  const unsigned short* Bp = BT + (size_t)(n0 + srow) * K + ksw;
  const size_t rstep = (size_t)64 * K;

  const int segx = ((quad ^ ((l15 >> 1) & 3)) << 4);
  int offA[4], offB[4];
  #pragma unroll
  for (int mf = 0; mf < 4; mf++) offA[mf] = (wr * 64 + mf * 16 + l15) * 64 + segx;
  #pragma unroll
  for (int nf = 0; nf < 4; nf++) offB[nf] = (wc * 64 + nf * 16 + l15) * 64 + segx;

  auto stage = [&](int tt, int kh, int b){
    const int coff = tt * 64 + kh * 32;
    char* Ad = SMc + b * 32768 + kh * 8192 + tid * 16;
    char* Bd = SMc + b * 32768 + 16384 + kh * 8192 + tid * 16;
    glds16(Ap + coff,         Ad);
    glds16(Ap + coff + rstep, Ad + 4096);
    glds16(Bp + coff,         Bd);
    glds16(Bp + coff + rstep, Bd + 4096);
  };

  s16x8 af[4], bf[4];
  auto rdfrags = [&](int b, int kh){
    const char* Ab = SMc + b * 32768 + kh * 8192;
    const char* Bb = SMc + b * 32768 + 16384 + kh * 8192;
    #pragma unroll
    for (int i = 0; i < 4; i++) af[i] = *(const s16x8*)(Ab + offA[i]);
    #pragma unroll
    for (int j = 0; j < 4; j++) bf[j] = *(const s16x8*)(Bb + offB[j]);
  };

  stage(0, 0, 0);
  stage(0, 1, 0);
  asm volatile("s_waitcnt vmcnt(4)" ::: "memory");
  asm volatile("s_barrier" ::: "memory");
  rdfrags(0, 0);

  for (int t = 0; t < T; ++t){
    const int cur = t & 1;
    if (t + 1 < T) stage(t + 1, 0, cur ^ 1);
    __builtin_amdgcn_s_setprio(1);
    #pragma unroll
    for (int i = 0; i < 4; i++)
      #pragma unroll
      for (int j = 0; j < 4; j++)
        acc[i][j] = __builtin_amdgcn_mfma_f32_16x16x32_bf16(af[i], bf[j], acc[i][j], 0, 0, 0);
    __builtin_amdgcn_s_setprio(0);
    if (t + 1 < T){ asm volatile("s_waitcnt vmcnt(4)" ::: "memory"); }
    else          { asm volatile("s_waitcnt vmcnt(0)" ::: "memory"); }
    asm volatile("s_barrier" ::: "memory");
    rdfrags(cur, 1);
    if (t + 1 < T) stage(t + 1, 1, cur ^ 1);
    __builtin_amdgcn_s_setprio(1);
    #pragma unroll
    for (int i = 0; i < 4; i++)
      #pragma unroll
      for (int j = 0; j < 4; j++)
        acc[i][j] = __builtin_amdgcn_mfma_f32_16x16x32_bf16(af[i], bf[j], acc[i][j], 0, 0, 0);
    __builtin_amdgcn_s_setprio(0);
    if (t + 1 < T){
      asm volatile("s_waitcnt vmcnt(4)" ::: "memory");
      asm volatile("s_barrier" ::: "memory");
      rdfrags(cur ^ 1, 0);
    }
  }
}

// ------- GEMM1: [16384x768] x [5376x768]^T -> q(rope)/k(rope)/v/comb(gelu) ---
__global__ __launch_bounds__(256, 2) void gemm1_k(
    const unsigned short* __restrict__ A, const unsigned short* __restrict__ BT,
    const float* __restrict__ bias,
    const float* __restrict__ psin, const float* __restrict__ pcos,
    unsigned short* __restrict__ qb, unsigned short* __restrict__ kb,
    unsigned short* __restrict__ vb, unsigned short* __restrict__ comb)
{
  __shared__ short SM[32768];
  const int tid = threadIdx.x, lane = tid & 63, wv = tid >> 6;
  const int quad = lane >> 4, l15 = lane & 15;
  const int wr = wv >> 1, wc = wv & 1;

  // XCD-ownership remap (dispatch assumed round-robin: phys p -> XCD p%8,
  // per learn_hip m09/m157). XCD x owns an m-band of 16 m-tiles; within an
  // XCD blocks are n-major, so the 3.1 MB A-band stays L2-resident (working
  // set 3.1 + ~4x0.2 MB streaming B < 4 MiB L2) and each B panel is fetched
  // ~once per XCD. Expected L2 fill ~ 8 x (3.1 + 8) = 90 MB (was 278 MB).
  // If the dispatch assumption is wrong this degenerates to current behavior.
  const int p = blockIdx.x + blockIdx.y * gridDim.x;   // 42*128 = 5376 blocks
  const int xcd = p & 7, slot = p >> 3;                // 672 slots per XCD
  const int m0 = (xcd * 16 + (slot & 15)) * 128;       // 16 m-tiles per band
  const int n0 = (slot >> 4) * 128;                    // n-major within XCD

  f32x4 acc[4][4];
  #pragma unroll
  for (int i = 0; i < 4; i++)
    #pragma unroll
    for (int j = 0; j < 4; j++) acc[i][j] = (f32x4){0.f,0.f,0.f,0.f};

  gemm_pipe2<HIDN>(A, BT, SM, tid, quad, l15, wr, wc, m0, n0, acc);

  // block-uniform output class (boundaries 768/1536/2304 are multiples of 128)
  unsigned short* dstb; int cb; int cls;
  if (n0 < 768)       { dstb = qb;   cb = n0;        cls = 0; }
  else if (n0 < 1536) { dstb = kb;   cb = n0 - 768;  cls = 1; }
  else if (n0 < 2304) { dstb = vb;   cb = n0 - 1536; cls = 2; }
  else                { dstb = comb; cb = n0 - 1536; cls = 3; }
  const int rowstride = (cls == 3) ? COMBN : HIDN;

  float bsv[4];
  #pragma unroll
  for (int nf = 0; nf < 4; nf++) bsv[nf] = bias[n0 + wc * 64 + nf * 16 + l15];

  if (cls <= 1){
    // q/k: fused RoPE (+1/8 scale for q). Pair partner of col c is c^1 ->
    // lane l15^1 (same nf): one shfl_xor. d = col%64 = nf*16+l15 (n0, cb,
    // wc*64 are multiples of 64), so sin/cos reads are 64-lane coalesced.
    const float qscale = (cls == 0) ? 0.125f : 1.0f;
    #pragma unroll
    for (int mf = 0; mf < 4; mf++){
      #pragma unroll
      for (int r = 0; r < 4; r++){
        const int row = m0 + wr * 64 + mf * 16 + quad * 4 + r;
        unsigned short* rp = dstb + (size_t)row * rowstride + cb + wc * 64;
        const float* sp = psin + (size_t)row * DHD;
        const float* cp = pcos + (size_t)row * DHD;
        #pragma unroll
        for (int nf = 0; nf < 4; nf++){
          const int d = nf * 16 + l15;
          float v = acc[mf][nf][r] + bsv[nf];
          float vp = __shfl_xor(v, 1);
          const float s = sp[d], c = cp[d];
          float o = (l15 & 1) ? (v * c + vp * s) : (v * c - vp * s);
          rp[d] = f2bf(o * qscale);
        }
      }
    }
  } else {
    // v / ff: unchanged (nf-INNER contiguous 128B row-runs)
    #pragma unroll
    for (int mf = 0; mf < 4; mf++){
      #pragma unroll
      for (int r = 0; r < 4; r++){
        const int row = m0 + wr * 64 + mf * 16 + quad * 4 + r;
        unsigned short* rp = dstb + (size_t)row * rowstride + cb + wc * 64;
        #pragma unroll
        for (int nf = 0; nf < 4; nf++){
          float val = acc[mf][nf][r] + bsv[nf];
          if (cls == 3) val = gelu_fast(val);
          rp[nf * 16 + l15] = f2bf(val);
        }
      }
    }
  }
}

// ------- GEMM2: [16384x3840] x [768x3840]^T + b + xn residual -> fp32 -------
__global__ __launch_bounds__(256, 2) void gemm2_k(
    const unsigned short* __restrict__ A, const unsigned short* __restrict__ BT,
    const float* __restrict__ bias, const unsigned short* __restrict__ xn,
    float* __restrict__ outp)
{
  __shared__ short SM[32768];
  const int tid = threadIdx.x, lane = tid & 63, wv = tid >> 6;
  const int quad = lane >> 4, l15 = lane & 15;
  const int wr = wv >> 1, wc = wv & 1;
  const int n0 = blockIdx.x * 128, m0 = blockIdx.y * 128;

  f32x4 acc[4][4];
  #pragma unroll
  for (int i = 0; i < 4; i++)
    #pragma unroll
    for (int j = 0; j < 4; j++) acc[i][j] = (f32x4){0.f,0.f,0.f,0.f};

  gemm_pipe2<COMBN>(A, BT, SM, tid, quad, l15, wr, wc, m0, n0, acc);

  float bsv[4];
  #pragma unroll
  for (int nf = 0; nf < 4; nf++) bsv[nf] = bias[n0 + wc * 64 + nf * 16 + l15];

  #pragma unroll
  for (int mf = 0; mf < 4; mf++){
    #pragma unroll
    for (int r = 0; r < 4; r++){
      const int row = m0 + wr * 64 + mf * 16 + quad * 4 + r;
      const size_t rb = (size_t)row * HIDN + n0 + wc * 64;
      #pragma unroll
      for (int nf = 0; nf < 4; nf++){
        const size_t o = rb + nf * 16 + l15;
        outp[o] = bf2f(xn[o]) + acc[mf][nf][r] + bsv[nf];
      }
    }
  }
}

// ------- chunked local attention: pre-roped Q/K [tok][768], 64-key tiles -------
__global__ __launch_bounds__(256) void attn_kernel(
    const unsigned short* __restrict__ qb, const unsigned short* __restrict__ kb,
    const unsigned short* __restrict__ vb, unsigned short* __restrict__ comb,
    const int* __restrict__ lenp)
{
  __shared__ short Ks[2][64 * 72];
  __shared__ short Vt[2][64 * 64];
  __shared__ short Ps[4][16 * 72];
  const int tid = threadIdx.x, lane = tid & 63, wv = tid >> 6;
  const int quad = lane >> 4, l15 = lane & 15;
  const int h = blockIdx.y, c = blockIdx.x;
  const unsigned lm = ~((unsigned)lenp[0] - 1u);
  const int i0 = c * CHUNK + wv * 64;
  const unsigned short* qh = qb + h * DHD;
  const unsigned short* kh = kb + h * DHD;
  const unsigned short* vh = vb + h * DHD;

  s16x8 qf[4][2];
  #pragma unroll
  for (int rt = 0; rt < 4; rt++){
    const unsigned short* qr = qh + (size_t)(i0 + rt * 16 + l15) * HIDN;
    qf[rt][0] = *(const s16x8*)(qr + quad * 8);
    qf[rt][1] = *(const s16x8*)(qr + 32 + quad * 8);
  }

  f32x4 O[4][4];
  float mm[4][4], ll[4][4];
  #pragma unroll
  for (int rt = 0; rt < 4; rt++)
    #pragma unroll
    for (int j = 0; j < 4; j++){ O[rt][j] = (f32x4){0,0,0,0}; mm[rt][j] = -1e30f; ll[rt][j] = 0.f; }
  short* myP = &Ps[wv][0];

  const int skey = tid & 63, sseg = tid >> 6;
  const int jb0 = c * CHUNK - 256;
  s16x8 kr[2], vr[2];

  auto issue = [&](int jb){
    if (jb >= 0){
      const unsigned short* kp = kh + (size_t)(jb + skey) * HIDN + sseg * 16;
      const unsigned short* vp = vh + (size_t)(jb + skey) * HIDN + sseg * 16;
      kr[0] = *(const s16x8*)(kp);     kr[1] = *(const s16x8*)(kp + 8);
      vr[0] = *(const s16x8*)(vp);     vr[1] = *(const s16x8*)(vp + 8);
    } else {
      kr[0] = kr[1] = vr[0] = vr[1] = (s16x8){0,0,0,0,0,0,0,0};
    }
  };

  issue(jb0);
  for (int tb = 0; tb < 8; tb++){
    const int jb = jb0 + tb * 64;
    const int buf = tb & 1;
    short* Kb = &Ks[buf][0];
    short* Vb = &Vt[buf][0];
    *(s16x8*)(Kb + skey * 72 + sseg * 16)     = kr[0];
    *(s16x8*)(Kb + skey * 72 + sseg * 16 + 8) = kr[1];
    #pragma unroll
    for (int half = 0; half < 2; half++)
      #pragma unroll
      for (int j = 0; j < 8; j++){
        const int d = sseg * 16 + half * 8 + j;
        Vb[d * 64 + (((skey & 56) ^ ((d & 7) << 3)) | (skey & 7))] = vr[half][j];
      }
    if (tb < 7) issue(jb + 64);
    __syncthreads();

    const bool act = (jb >= 0) && (jb <= i0 + 63) && (jb + 63 >= i0 - 255) &&
                     (((unsigned)i0 & lm) == ((unsigned)jb & lm));
    if (!act) continue;

    #pragma unroll
    for (int rt = 0; rt < 4; rt++){
      const int ilo = i0 + rt * 16;
      if (ilo + 15 < jb || ilo - (jb + 63) >= WIN) continue;
      f32x4 sc[4];
      #pragma unroll
      for (int ct = 0; ct < 4; ct++){
        const short* kbase = Kb + (ct * 16 + l15) * 72 + quad * 8;
        const s16x8 b0 = *(const s16x8*)(kbase);
        const s16x8 b1 = *(const s16x8*)(kbase + 32);
        f32x4 aa = (f32x4){0,0,0,0};
        aa = __builtin_amdgcn_mfma_f32_16x16x32_bf16(qf[rt][0], b0, aa, 0, 0, 0);
        aa = __builtin_amdgcn_mfma_f32_16x16x32_bf16(qf[rt][1], b1, aa, 0, 0, 0);
        sc[ct] = aa;
      }
      float alph[4];
      #pragma unroll
      for (int r = 0; r < 4; r++){
        const int i = ilo + quad * 4 + r;
        #pragma unroll
        for (int ct = 0; ct < 4; ct++){
          const unsigned dd = (unsigned)(i - (jb + ct * 16 + l15));
          if (dd >= 256u) sc[ct][r] = -1e30f;
        }
        float mx = fmaxf(fmaxf(sc[0][r], sc[1][r]), fmaxf(sc[2][r], sc[3][r]));
        mx = fmaxf(mx, __shfl_xor(mx, 1));
        mx = fmaxf(mx, __shfl_xor(mx, 2));
        mx = fmaxf(mx, __shfl_xor(mx, 4));
        mx = fmaxf(mx, __shfl_xor(mx, 8));
        const float mnew = fmaxf(mm[rt][r], mx);
        alph[r] = __expf(mm[rt][r] - mnew);
        mm[rt][r] = mnew;
        float p0 = __expf(sc[0][r] - mnew);
        float p1 = __expf(sc[1][r] - mnew);
        float p2 = __expf(sc[2][r] - mnew);
        float p3 = __expf(sc[3][r] - mnew);
        sc[0][r] = p0; sc[1][r] = p1; sc[2][r] = p2; sc[3][r] = p3;
        float rsum = (p0 + p1) + (p2 + p3);
        rsum += __shfl_xor(rsum, 1);
        rsum += __shfl_xor(rsum, 2);
        rsum += __shfl_xor(rsum, 4);
        rsum += __shfl_xor(rsum, 8);
        ll[rt][r] = ll[rt][r] * alph[r] + rsum;
      }
      #pragma unroll
      for (int co = 0; co < 4; co++)
        #pragma unroll
        for (int r = 0; r < 4; r++) O[rt][co][r] *= alph[r];
      #pragma unroll
      for (int r = 0; r < 4; r++){
        const int prow = quad * 4 + r;
        #pragma unroll
        for (int ct = 0; ct < 4; ct++)
          myP[prow * 72 + ct * 16 + l15] = (short)f2bf(sc[ct][r]);
      }
      #pragma unroll
      for (int ks2 = 0; ks2 < 2; ks2++){
        const s16x8 pf = *(const s16x8*)(myP + l15 * 72 + ks2 * 32 + quad * 8);
        #pragma unroll
        for (int co = 0; co < 4; co++){
          const int d = co * 16 + l15;
          const s16x8 vf = *(const s16x8*)(Vb + d * 64 +
                              ((ks2 * 32 + quad * 8) ^ ((d & 7) << 3)));
          O[rt][co] = __builtin_amdgcn_mfma_f32_16x16x32_bf16(pf, vf, O[rt][co], 0, 0, 0);
        }
      }
    }
  }

  #pragma unroll
  for (int rt = 0; rt < 4; rt++)
    #pragma unroll
    for (int co = 0; co < 4; co++)
      #pragma unroll
      for (int r = 0; r < 4; r++){
        const int tok = i0 + rt * 16 + quad * 4 + r;
        comb[(size_t)tok * COMBN + h * DHD + co * 16 + l15] = f2bf(O[rt][co][r] / ll[rt][r]);
      }
}

extern "C" void kernel_launch(void* const* d_in, const int* in_sizes, int n_in,
                              void* d_out, int out_size, void* d_ws, size_t ws_size,
                              hipStream_t stream)
{
  const float* x     = (const float*)d_in[0];
  const float* psin  = (const float*)d_in[2];
  const float* pcos  = (const float*)d_in[3];
  const float* lns   = (const float*)d_in[4];
  const float* lno   = (const float*)d_in[5];
  const float* w_in  = (const float*)d_in[6];
  const float* b_in  = (const float*)d_in[7];
  const float* w_out = (const float*)d_in[8];
  const float* b_out = (const float*)d_in[9];
  const int*   lenp  = (const int*)d_in[10];
  float* out = (float*)d_out;

  char* ws = (char*)d_ws;
  size_t off = 0;
  unsigned short* xn    = (unsigned short*)(ws + off); off += (size_t)N_TOK * HIDN * 2;
  unsigned short* wInT  = (unsigned short*)(ws + off); off += (size_t)MIDN * HIDN * 2;
  unsigned short* wOutT = (unsigned short*)(ws + off); off += (size_t)HIDN * COMBN * 2;
  unsigned short* qbuf  = (unsigned short*)(ws + off); off += (size_t)N_TOK * HIDN * 2;
  unsigned short* kbuf  = (unsigned short*)(ws + off); off += (size_t)N_TOK * HIDN * 2;
  unsigned short* vbuf  = (unsigned short*)(ws + off); off += (size_t)N_TOK * HIDN * 2;
  unsigned short* comb  = (unsigned short*)(ws + off); off += (size_t)N_TOK * COMBN * 2;

  transpose_f2b<<<dim3(MIDN/64, HIDN/64), 256, 0, stream>>>(w_in, wInT, HIDN, MIDN);
  transpose_f2b<<<dim3(HIDN/64, COMBN/64), 256, 0, stream>>>(w_out, wOutT, COMBN, HIDN);
  ln_kernel<<<dim3(N_TOK/4), 256, 0, stream>>>(x, lns, lno, xn);
  gemm1_k<<<dim3(MIDN/128, N_TOK/128), 256, 0, stream>>>(
      xn, wInT, b_in, psin, pcos, qbuf, kbuf, vbuf, comb);
  attn_kernel<<<dim3(N_TOK/CHUNK, NH), 256, 0, stream>>>(
      qbuf, kbuf, vbuf, comb, lenp);
  gemm2_k<<<dim3(HIDN/128, N_TOK/128), 256, 0, stream>>>(
      comb, wOutT, b_out, xn, out);
}